// Round 2
// baseline (1603.715 us; speedup 1.0000x reference)
//
#include <hip/hip_runtime.h>

#define NN 4096
#define EE 262144
#define INF_ 64
#define HH 128
#define HEADS 4
#define DH 32
#define LL 2
#define NH (NN * HH)

typedef unsigned short u16;
typedef unsigned int u32;

__device__ __forceinline__ float bf2f(u16 v) { return __uint_as_float(((u32)v) << 16); }
__device__ __forceinline__ u16 f2bf(float f) {
    u32 u = __float_as_uint(f);
    u32 r = (u + 0x7fffu + ((u >> 16) & 1u)) >> 16;
    return (u16)r;
}

// ---------------- dtype detect + convert ----------------
// If inputs are bf16, even u16 halves of x are real values (exponent ~127).
// If inputs are f32, even u16 halves are random mantissa bits (~16% plausible).
__global__ __launch_bounds__(256) void k_detect(const u16* __restrict__ x, int* __restrict__ flag) {
    __shared__ int cs[256];
    int t = threadIdx.x;
    u16 v = x[2 * t];
    int e = (v >> 7) & 0xFF;
    cs[t] = (e >= 100 && e <= 140) ? 1 : 0;
    __syncthreads();
    for (int s = 128; s > 0; s >>= 1) {
        if (t < s) cs[t] += cs[t + s];
        __syncthreads();
    }
    if (t == 0) *flag = (cs[0] >= 128) ? 1 : 0;
}

__global__ void k_cvt(const void* __restrict__ src, float* __restrict__ dst, int n,
                      const int* __restrict__ flag) {
    int i = blockIdx.x * blockDim.x + threadIdx.x;
    if (i >= n) return;
    if (*flag)
        dst[i] = bf2f(((const u16*)src)[i]);
    else
        dst[i] = ((const float*)src)[i];
}

// ---------------- CSR build ----------------
__global__ void k_zero(int* cnt) {
    int t = blockIdx.x * blockDim.x + threadIdx.x;
    if (t < NN) cnt[t] = 0;
}
__global__ void k_hist(const int* __restrict__ dst, int* __restrict__ cnt) {
    int e = blockIdx.x * blockDim.x + threadIdx.x;
    if (e < EE) atomicAdd(&cnt[dst[e]], 1);
}
__global__ __launch_bounds__(256) void k_scan(const int* __restrict__ cnt, int* __restrict__ rowstart,
                                              int* __restrict__ cursor) {
    __shared__ int part[256];
    int t = threadIdx.x;
    int loc[16];
    int s = 0;
#pragma unroll
    for (int i = 0; i < 16; ++i) { loc[i] = s; s += cnt[t * 16 + i]; }
    part[t] = s;
    __syncthreads();
    for (int off = 1; off < 256; off <<= 1) {
        int v = part[t];
        int a = (t >= off) ? part[t - off] : 0;
        __syncthreads();
        part[t] = v + a;
        __syncthreads();
    }
    int base = (t == 0) ? 0 : part[t - 1];
#pragma unroll
    for (int i = 0; i < 16; ++i) {
        rowstart[t * 16 + i] = base + loc[i];
        cursor[t * 16 + i] = base + loc[i];
    }
}
__global__ void k_scatter(const int* __restrict__ src, const int* __restrict__ dst,
                          int* __restrict__ cursor, int* __restrict__ esrc) {
    int e = blockIdx.x * blockDim.x + threadIdx.x;
    if (e < EE) {
        int d = dst[e];
        int p = atomicAdd(&cursor[d], 1);
        esrc[p] = src[e];
    }
}

// ---------------- dense layers (f32 params) ----------------
__global__ __launch_bounds__(128) void k_in_proj(const float* __restrict__ x, const float* __restrict__ w,
                                                 const float* __restrict__ b, float* __restrict__ h) {
    __shared__ float sx[INF_];
    int n = blockIdx.x, j = threadIdx.x;
    if (j < INF_) sx[j] = x[n * INF_ + j];
    __syncthreads();
    float acc = b[j];
    const float4* wr = (const float4*)(w + (size_t)j * INF_);
#pragma unroll
    for (int kk = 0; kk < INF_ / 4; ++kk) {
        float4 u = wr[kk];
        acc += sx[4 * kk + 0] * u.x;
        acc += sx[4 * kk + 1] * u.y;
        acc += sx[4 * kk + 2] * u.z;
        acc += sx[4 * kk + 3] * u.w;
    }
    h[(size_t)n * HH + j] = fmaxf(acc, 0.f);
}

// out[n][j] = (relu?) sum_k in[n][k] * w[j][k] + b[j]; grid=N, block=J, K<=256
__global__ void k_gemm(const float* __restrict__ in, const float* __restrict__ w,
                       const float* __restrict__ b, float* __restrict__ out, int K, int relu) {
    __shared__ float srow[256];
    int n = blockIdx.x;
    int J = blockDim.x;
    int j = threadIdx.x;
    for (int k = threadIdx.x; k < K; k += J) srow[k] = in[(size_t)n * K + k];
    __syncthreads();
    float acc = b ? b[j] : 0.f;
    const float4* wr = (const float4*)(w + (size_t)j * K);
    int kq = K >> 2;
#pragma unroll 4
    for (int kk = 0; kk < kq; ++kk) {
        float4 u = wr[kk];
        acc += srow[4 * kk + 0] * u.x;
        acc += srow[4 * kk + 1] * u.y;
        acc += srow[4 * kk + 2] * u.z;
        acc += srow[4 * kk + 3] * u.w;
    }
    if (relu) acc = fmaxf(acc, 0.f);
    out[(size_t)n * J + j] = acc;
}

__global__ void k_attlog(const float* __restrict__ xp, const float* __restrict__ asrc,
                         const float* __restrict__ adst, float* __restrict__ als, float* __restrict__ ald) {
    int t = blockIdx.x * blockDim.x + threadIdx.x;
    if (t >= NN * HEADS) return;
    int n = t >> 2, hh = t & 3;
    const float* xr = xp + (size_t)n * HH + hh * DH;
    float s1 = 0.f, s2 = 0.f;
#pragma unroll
    for (int d = 0; d < DH; ++d) {
        float v = xr[d];
        s1 += v * asrc[hh * DH + d];
        s2 += v * adst[hh * DH + d];
    }
    als[t] = s1;
    ald[t] = s2;
}

// ---------------- GAT per-node softmax + aggregation (no atomics) ----------------
__global__ __launch_bounds__(128) void k_gat_node(const int* __restrict__ esrc, const int* __restrict__ rowstart,
                                                  const int* __restrict__ cnt, const float* __restrict__ als,
                                                  const float* __restrict__ ald, const float* __restrict__ xp,
                                                  float* __restrict__ gatout) {
    int n = blockIdx.x, t = threadIdx.x;
    int base = rowstart[n], c = cnt[n];
    float4 adv = ((const float4*)ald)[n];
    float ad[4] = {adv.x, adv.y, adv.z, adv.w};
    __shared__ float red[512];
    // phase A: max
    float mx[4] = {-INFINITY, -INFINITY, -INFINITY, -INFINITY};
    for (int i = t; i < c; i += 128) {
        int s = esrc[base + i];
        float4 as = ((const float4*)als)[s];
        float lg;
        lg = as.x + ad[0]; lg = lg >= 0.f ? lg : 0.2f * lg; mx[0] = fmaxf(mx[0], lg);
        lg = as.y + ad[1]; lg = lg >= 0.f ? lg : 0.2f * lg; mx[1] = fmaxf(mx[1], lg);
        lg = as.z + ad[2]; lg = lg >= 0.f ? lg : 0.2f * lg; mx[2] = fmaxf(mx[2], lg);
        lg = as.w + ad[3]; lg = lg >= 0.f ? lg : 0.2f * lg; mx[3] = fmaxf(mx[3], lg);
    }
#pragma unroll
    for (int h = 0; h < 4; ++h) red[h * 128 + t] = mx[h];
    __syncthreads();
    for (int s2 = 64; s2 > 0; s2 >>= 1) {
        if (t < s2) {
#pragma unroll
            for (int h = 0; h < 4; ++h)
                red[h * 128 + t] = fmaxf(red[h * 128 + t], red[h * 128 + t + s2]);
        }
        __syncthreads();
    }
    float m4[4];
#pragma unroll
    for (int h = 0; h < 4; ++h) m4[h] = red[h * 128];
    __syncthreads();
    // phase B: denom
    float sm[4] = {0.f, 0.f, 0.f, 0.f};
    for (int i = t; i < c; i += 128) {
        int s = esrc[base + i];
        float4 as = ((const float4*)als)[s];
        float lg;
        lg = as.x + ad[0]; lg = lg >= 0.f ? lg : 0.2f * lg; sm[0] += __expf(lg - m4[0]);
        lg = as.y + ad[1]; lg = lg >= 0.f ? lg : 0.2f * lg; sm[1] += __expf(lg - m4[1]);
        lg = as.z + ad[2]; lg = lg >= 0.f ? lg : 0.2f * lg; sm[2] += __expf(lg - m4[2]);
        lg = as.w + ad[3]; lg = lg >= 0.f ? lg : 0.2f * lg; sm[3] += __expf(lg - m4[3]);
    }
#pragma unroll
    for (int h = 0; h < 4; ++h) red[h * 128 + t] = sm[h];
    __syncthreads();
    for (int s2 = 64; s2 > 0; s2 >>= 1) {
        if (t < s2) {
#pragma unroll
            for (int h = 0; h < 4; ++h)
                red[h * 128 + t] += red[h * 128 + t + s2];
        }
        __syncthreads();
    }
    float inv[4];
#pragma unroll
    for (int h = 0; h < 4; ++h) inv[h] = 1.f / (red[h * 128] + 1e-16f);
    // phase C: aggregate; thread t owns feature dim t, head = t>>5
    int ht = t >> 5;
    float mloc = m4[ht], invloc = inv[ht], adloc = ad[ht];
    float acc = 0.f;
    for (int i = 0; i < c; ++i) {
        int s = esrc[base + i];
        float lg = als[s * 4 + ht] + adloc;
        lg = lg >= 0.f ? lg : 0.2f * lg;
        float alpha = __expf(lg - mloc) * invloc;
        acc += alpha * xp[(size_t)s * HH + t];
    }
    gatout[(size_t)n * HH + t] = acc;
}

// ---------------- MHA flash (f32 VALU) ----------------
__global__ __launch_bounds__(256) void k_mha(const float* __restrict__ qkv, float* __restrict__ out) {
    int head = blockIdx.x & 3;
    int qblk = blockIdx.x >> 2;
    int wave = threadIdx.x >> 6, lane = threadIdx.x & 63;
    int q0 = qblk * 8 + wave * 2;
    __shared__ float klds[DH * 64];
    __shared__ float vlds[DH * 64];
    float qa[DH], qb[DH];
    const float* qp = qkv + (size_t)q0 * 384 + head * DH;
#pragma unroll
    for (int d = 0; d < DH; ++d) { qa[d] = qp[d]; qb[d] = qp[384 + d]; }
    float m0 = -INFINITY, m1 = -INFINITY, l0 = 0.f, l1 = 0.f;
    float acc0[DH], acc1[DH];
#pragma unroll
    for (int d = 0; d < DH; ++d) { acc0[d] = 0.f; acc1[d] = 0.f; }
    int skey = threadIdx.x & 63, part = threadIdx.x >> 6;
    const float* kbase = qkv + 128 + head * DH + part * 8;
    for (int kt = 0; kt < NN; kt += 64) {
        __syncthreads();
        const float* kp = kbase + (size_t)(kt + skey) * 384;
        float4 ka = *(const float4*)kp;
        float4 kb = *(const float4*)(kp + 4);
        float4 va = *(const float4*)(kp + 128);
        float4 vb = *(const float4*)(kp + 132);
        int wb = part * 8;
        klds[(wb + 0) * 64 + skey] = ka.x; klds[(wb + 1) * 64 + skey] = ka.y;
        klds[(wb + 2) * 64 + skey] = ka.z; klds[(wb + 3) * 64 + skey] = ka.w;
        klds[(wb + 4) * 64 + skey] = kb.x; klds[(wb + 5) * 64 + skey] = kb.y;
        klds[(wb + 6) * 64 + skey] = kb.z; klds[(wb + 7) * 64 + skey] = kb.w;
        vlds[(wb + 0) * 64 + skey] = va.x; vlds[(wb + 1) * 64 + skey] = va.y;
        vlds[(wb + 2) * 64 + skey] = va.z; vlds[(wb + 3) * 64 + skey] = va.w;
        vlds[(wb + 4) * 64 + skey] = vb.x; vlds[(wb + 5) * 64 + skey] = vb.y;
        vlds[(wb + 6) * 64 + skey] = vb.z; vlds[(wb + 7) * 64 + skey] = vb.w;
        __syncthreads();
        float s0 = 0.f, s1 = 0.f;
#pragma unroll
        for (int d = 0; d < DH; ++d) {
            float kd = klds[d * 64 + lane];
            s0 += qa[d] * kd;
            s1 += qb[d] * kd;
        }
        s0 *= 0.17677669529663687f;
        s1 *= 0.17677669529663687f;
        float nm0 = fmaxf(m0, s0), nm1 = fmaxf(m1, s1);
        float c0 = __expf(m0 - nm0), c1 = __expf(m1 - nm1);
        float p0 = __expf(s0 - nm0), p1 = __expf(s1 - nm1);
        l0 = l0 * c0 + p0; l1 = l1 * c1 + p1;
        m0 = nm0; m1 = nm1;
#pragma unroll
        for (int d = 0; d < DH; ++d) {
            float vd = vlds[d * 64 + lane];
            acc0[d] = acc0[d] * c0 + p0 * vd;
            acc1[d] = acc1[d] * c1 + p1 * vd;
        }
    }
#pragma unroll
    for (int off = 1; off < 64; off <<= 1) {
        float om0 = __shfl_xor(m0, off), ol0 = __shfl_xor(l0, off);
        float om1 = __shfl_xor(m1, off), ol1 = __shfl_xor(l1, off);
        float nm0 = fmaxf(m0, om0), nm1 = fmaxf(m1, om1);
        float cs0 = __expf(m0 - nm0), co0 = __expf(om0 - nm0);
        float cs1 = __expf(m1 - nm1), co1 = __expf(om1 - nm1);
        l0 = l0 * cs0 + ol0 * co0;
        l1 = l1 * cs1 + ol1 * co1;
#pragma unroll
        for (int d = 0; d < DH; ++d) {
            float oa = __shfl_xor(acc0[d], off);
            acc0[d] = acc0[d] * cs0 + oa * co0;
            float ob = __shfl_xor(acc1[d], off);
            acc1[d] = acc1[d] * cs1 + ob * co1;
        }
        m0 = nm0; m1 = nm1;
    }
    if (lane == 0) {
        float i0 = 1.f / l0, i1 = 1.f / l1;
        float* o0 = out + (size_t)q0 * HH + head * DH;
#pragma unroll
        for (int d = 0; d < DH; ++d) {
            o0[d] = acc0[d] * i0;
            o0[HH + d] = acc1[d] * i1;
        }
    }
}

// ---------------- elementwise combine / final ----------------
__global__ void k_combine(const float* __restrict__ gat, const float* __restrict__ proj,
                          const float* __restrict__ h, const float* __restrict__ bgat,
                          const float* __restrict__ gam, const float* __restrict__ bet,
                          float* __restrict__ outb) {
    int t = blockIdx.x * blockDim.x + threadIdx.x;
    if (t >= NN * HH) return;
    int j = t & (HH - 1);
    float rs = rsqrtf(1.00001f);
    float g0 = gam[j] * rs, b0 = bet[j];
    float g1 = gam[HH + j] * rs, b1 = bet[HH + j];
    float hv = h[t];
    float hl = g0 * (gat[t] + bgat[j] + hv) + b0;
    float ha = g1 * (proj[t] + hv) + b1;
    outb[t] = hl + ha;
}

__global__ void k_final(const float* __restrict__ outb, const float* __restrict__ mlpo,
                        const float* __restrict__ gam, const float* __restrict__ bet,
                        float* __restrict__ h) {
    int t = blockIdx.x * blockDim.x + threadIdx.x;
    if (t >= NN * HH) return;
    int j = t & (HH - 1);
    float rs = rsqrtf(1.00001f);
    float g2 = gam[2 * HH + j] * rs, b2 = bet[2 * HH + j];
    float o2 = g2 * (outb[t] + mlpo[t]) + b2;
    h[t] = fmaxf(o2 + h[t], 0.f);
}

// ---------------- output projection (dtype-adaptive store) ----------------
__global__ __launch_bounds__(64) void k_out(const float* __restrict__ h, const float* __restrict__ w,
                                            const float* __restrict__ b, void* __restrict__ yout,
                                            const int* __restrict__ flag) {
    int n = blockIdx.x, l = threadIdx.x;
    float a0 = 0.f, a1 = 0.f;
    for (int k = l; k < HH; k += 64) {
        float hv = h[(size_t)n * HH + k];
        a0 += hv * w[k];
        a1 += hv * w[HH + k];
    }
#pragma unroll
    for (int off = 32; off > 0; off >>= 1) {
        a0 += __shfl_xor(a0, off);
        a1 += __shfl_xor(a1, off);
    }
    if (l == 0) {
        float o0 = a0 + b[0], o1 = a1 + b[1];
        if (*flag) {
            u16* y = (u16*)yout;
            y[n * 2 + 0] = f2bf(o0);
            y[n * 2 + 1] = f2bf(o1);
        } else {
            float* y = (float*)yout;
            y[n * 2 + 0] = o0;
            y[n * 2 + 1] = o1;
        }
    }
}

extern "C" void kernel_launch(void* const* d_in, const int* in_sizes, int n_in,
                              void* d_out, int out_size, void* d_ws, size_t ws_size,
                              hipStream_t stream) {
    float* W = (float*)d_ws;
    // ---- param region layout (floats) ----
    size_t o = 0;
    auto take = [&](size_t n) { size_t r = o; o += n; return r; };
    size_t px    = take(NN * INF_);      // 262144
    size_t pw_in = take(HH * INF_);      // 8192
    size_t pb_in = take(HH);
    size_t pw_gat = take(LL * HH * HH);  // 32768
    size_t pattS  = take(LL * HEADS * DH);
    size_t pattD  = take(LL * HEADS * DH);
    size_t pb_gat = take(LL * HH);
    size_t pw_qkv = take(LL * 3 * HH * HH);  // 98304
    size_t pb_qkv = take(LL * 3 * HH);
    size_t pw_o   = take(LL * HH * HH);
    size_t pb_o   = take(LL * HH);
    size_t pbn_g  = take(LL * 3 * HH);
    size_t pbn_b  = take(LL * 3 * HH);
    size_t pw1    = take(LL * 2 * HH * HH);
    size_t pb1    = take(LL * 2 * HH);
    size_t pw2    = take(LL * HH * 2 * HH);
    size_t pb2    = take(LL * HH);
    size_t pw_out = take(2 * HH);
    size_t pb_out = take(2);
    o = (o + 127) & ~(size_t)127;
    size_t ohbuf = take(NH);
    size_t ogat  = take(NH);
    size_t obig  = take(3 * NH);
    size_t otmp  = take(NH);
    size_t oals  = take(NN * HEADS);
    size_t oald  = take(NN * HEADS);
    int* ibase    = (int*)(W + o);
    int* iflag    = ibase;
    int* cnt      = ibase + 64;
    int* rowstart = cnt + NN;
    int* cursor   = rowstart + NN;
    int* esrc     = cursor + NN;

    float* hbuf = W + ohbuf;
    float* gatb = W + ogat;
    float* big  = W + obig;   // qkv -> (projb | mlph | mlpo)
    float* tmp  = W + otmp;   // xp -> attno -> outbuf
    float* als  = W + oals;
    float* ald  = W + oald;

    const int* src = (const int*)d_in[1];
    const int* dst = (const int*)d_in[1] + EE;

    // ---- dtype detect + param conversion ----
    k_detect<<<1, 256, 0, stream>>>((const u16*)d_in[0], iflag);
    struct { int idx; size_t off; int n; } cv[] = {
        {0,  px,    NN * INF_},      {2,  pw_in, HH * INF_},     {3,  pb_in, HH},
        {4,  pw_gat, LL * HH * HH},  {5,  pattS, LL * HEADS * DH},
        {6,  pattD, LL * HEADS * DH},{7,  pb_gat, LL * HH},
        {8,  pw_qkv, LL * 3 * HH * HH}, {9, pb_qkv, LL * 3 * HH},
        {10, pw_o,  LL * HH * HH},   {11, pb_o,  LL * HH},
        {12, pbn_g, LL * 3 * HH},    {13, pbn_b, LL * 3 * HH},
        {14, pw1,   LL * 2 * HH * HH}, {15, pb1, LL * 2 * HH},
        {16, pw2,   LL * HH * 2 * HH}, {17, pb2, LL * HH},
        {18, pw_out, 2 * HH},        {19, pb_out, 2},
    };
    for (auto& c : cv)
        k_cvt<<<(c.n + 255) / 256, 256, 0, stream>>>(d_in[c.idx], W + c.off, c.n, iflag);

    // ---- CSR build ----
    k_zero<<<16, 256, 0, stream>>>(cnt);
    k_hist<<<EE / 256, 256, 0, stream>>>(dst, cnt);
    k_scan<<<1, 256, 0, stream>>>(cnt, rowstart, cursor);
    k_scatter<<<EE / 256, 256, 0, stream>>>(src, dst, cursor, esrc);

    k_in_proj<<<NN, 128, 0, stream>>>(W + px, W + pw_in, W + pb_in, hbuf);

    for (int l = 0; l < LL; ++l) {
        // GAT branch: xp -> tmp
        k_gemm<<<NN, HH, 0, stream>>>(hbuf, W + pw_gat + (size_t)l * HH * HH, nullptr, tmp, HH, 0);
        k_attlog<<<(NN * HEADS) / 256, 256, 0, stream>>>(tmp, W + pattS + l * HEADS * DH,
                                                         W + pattD + l * HEADS * DH, als, ald);
        k_gat_node<<<NN, 128, 0, stream>>>(esrc, rowstart, cnt, als, ald, tmp, gatb);
        // MHA branch: qkv -> big; attno -> tmp (xp dead); projb -> big (qkv dead)
        k_gemm<<<NN, 3 * HH, 0, stream>>>(hbuf, W + pw_qkv + (size_t)l * 3 * HH * HH,
                                          W + pb_qkv + l * 3 * HH, big, HH, 0);
        k_mha<<<(NN / 8) * HEADS, 256, 0, stream>>>(big, tmp);
        k_gemm<<<NN, HH, 0, stream>>>(tmp, W + pw_o + (size_t)l * HH * HH, W + pb_o + l * HH,
                                      big, HH, 0);
        // combine -> tmp (attno dead)
        k_combine<<<(NN * HH) / 256, 256, 0, stream>>>(gatb, big, hbuf, W + pb_gat + l * HH,
                                                       W + pbn_g + l * 3 * HH, W + pbn_b + l * 3 * HH,
                                                       tmp);
        // MLP: mlph -> big[0:2NH] (projb dead), mlpo -> big+2NH
        k_gemm<<<NN, 2 * HH, 0, stream>>>(tmp, W + pw1 + (size_t)l * 2 * HH * HH,
                                          W + pb1 + l * 2 * HH, big, HH, 1);
        k_gemm<<<NN, HH, 0, stream>>>(big, W + pw2 + (size_t)l * HH * 2 * HH, W + pb2 + l * HH,
                                      big + 2 * (size_t)NH, 2 * HH, 0);
        k_final<<<(NN * HH) / 256, 256, 0, stream>>>(tmp, big + 2 * (size_t)NH,
                                                     W + pbn_g + l * 3 * HH, W + pbn_b + l * 3 * HH,
                                                     hbuf);
    }
    k_out<<<NN, 64, 0, stream>>>(hbuf, W + pw_out, W + pb_out, d_out, iflag);
}

// Round 3
// 991.052 us; speedup vs baseline: 1.6182x; 1.6182x over previous
//
#include <hip/hip_runtime.h>

#define NN 4096
#define EE 262144
#define INF_ 64
#define HH 128
#define HEADS 4
#define DH 32
#define LL 2
#define NH (NN * HH)

typedef unsigned short u16;
typedef unsigned int u32;
using bf16x8 = __attribute__((ext_vector_type(8))) short;
using f32x4 = __attribute__((ext_vector_type(4))) float;

__device__ __forceinline__ float bf2f(u16 v) { return __uint_as_float(((u32)v) << 16); }
__device__ __forceinline__ u16 f2bf(float f) {
    u32 u = __float_as_uint(f);
    u32 r = (u + 0x7fffu + ((u >> 16) & 1u)) >> 16;
    return (u16)r;
}

// ---------------- dtype detect + convert ----------------
__global__ __launch_bounds__(256) void k_detect(const u16* __restrict__ x, int* __restrict__ flag) {
    __shared__ int cs[256];
    int t = threadIdx.x;
    u16 v = x[2 * t];
    int e = (v >> 7) & 0xFF;
    cs[t] = (e >= 100 && e <= 140) ? 1 : 0;
    __syncthreads();
    for (int s = 128; s > 0; s >>= 1) {
        if (t < s) cs[t] += cs[t + s];
        __syncthreads();
    }
    if (t == 0) *flag = (cs[0] >= 128) ? 1 : 0;
}

__global__ void k_cvt(const void* __restrict__ src, float* __restrict__ dst, int n,
                      const int* __restrict__ flag) {
    int i = blockIdx.x * blockDim.x + threadIdx.x;
    if (i >= n) return;
    if (*flag)
        dst[i] = bf2f(((const u16*)src)[i]);
    else
        dst[i] = ((const float*)src)[i];
}

__global__ void k_f2b(const float* __restrict__ src, u16* __restrict__ dst, int n) {
    int i = blockIdx.x * blockDim.x + threadIdx.x;
    if (i < n) dst[i] = f2bf(src[i]);
}

// ---------------- CSR build ----------------
__global__ void k_zero(int* cnt) {
    int t = blockIdx.x * blockDim.x + threadIdx.x;
    if (t < NN) cnt[t] = 0;
}
__global__ void k_hist(const int* __restrict__ dst, int* __restrict__ cnt) {
    int e = blockIdx.x * blockDim.x + threadIdx.x;
    if (e < EE) atomicAdd(&cnt[dst[e]], 1);
}
__global__ __launch_bounds__(256) void k_scan(const int* __restrict__ cnt, int* __restrict__ rowstart,
                                              int* __restrict__ cursor) {
    __shared__ int part[256];
    int t = threadIdx.x;
    int loc[16];
    int s = 0;
#pragma unroll
    for (int i = 0; i < 16; ++i) { loc[i] = s; s += cnt[t * 16 + i]; }
    part[t] = s;
    __syncthreads();
    for (int off = 1; off < 256; off <<= 1) {
        int v = part[t];
        int a = (t >= off) ? part[t - off] : 0;
        __syncthreads();
        part[t] = v + a;
        __syncthreads();
    }
    int base = (t == 0) ? 0 : part[t - 1];
#pragma unroll
    for (int i = 0; i < 16; ++i) {
        rowstart[t * 16 + i] = base + loc[i];
        cursor[t * 16 + i] = base + loc[i];
    }
}
__global__ void k_scatter(const int* __restrict__ src, const int* __restrict__ dst,
                          int* __restrict__ cursor, int* __restrict__ esrc) {
    int e = blockIdx.x * blockDim.x + threadIdx.x;
    if (e < EE) {
        int d = dst[e];
        int p = atomicAdd(&cursor[d], 1);
        esrc[p] = src[e];
    }
}

// ---------------- dense layers (f32 params) ----------------
__global__ __launch_bounds__(128) void k_in_proj(const float* __restrict__ x, const float* __restrict__ w,
                                                 const float* __restrict__ b, float* __restrict__ h) {
    __shared__ float sx[INF_];
    int n = blockIdx.x, j = threadIdx.x;
    if (j < INF_) sx[j] = x[n * INF_ + j];
    __syncthreads();
    float acc = b[j];
    const float4* wr = (const float4*)(w + (size_t)j * INF_);
#pragma unroll
    for (int kk = 0; kk < INF_ / 4; ++kk) {
        float4 u = wr[kk];
        acc += sx[4 * kk + 0] * u.x;
        acc += sx[4 * kk + 1] * u.y;
        acc += sx[4 * kk + 2] * u.z;
        acc += sx[4 * kk + 3] * u.w;
    }
    h[(size_t)n * HH + j] = fmaxf(acc, 0.f);
}

__global__ void k_gemm(const float* __restrict__ in, const float* __restrict__ w,
                       const float* __restrict__ b, float* __restrict__ out, int K, int relu) {
    __shared__ float srow[256];
    int n = blockIdx.x;
    int J = blockDim.x;
    int j = threadIdx.x;
    for (int k = threadIdx.x; k < K; k += J) srow[k] = in[(size_t)n * K + k];
    __syncthreads();
    float acc = b ? b[j] : 0.f;
    const float4* wr = (const float4*)(w + (size_t)j * K);
    int kq = K >> 2;
#pragma unroll 4
    for (int kk = 0; kk < kq; ++kk) {
        float4 u = wr[kk];
        acc += srow[4 * kk + 0] * u.x;
        acc += srow[4 * kk + 1] * u.y;
        acc += srow[4 * kk + 2] * u.z;
        acc += srow[4 * kk + 3] * u.w;
    }
    if (relu) acc = fmaxf(acc, 0.f);
    out[(size_t)n * J + j] = acc;
}

__global__ void k_attlog(const float* __restrict__ xp, const float* __restrict__ asrc,
                         const float* __restrict__ adst, float* __restrict__ als, float* __restrict__ ald) {
    int t = blockIdx.x * blockDim.x + threadIdx.x;
    if (t >= NN * HEADS) return;
    int n = t >> 2, hh = t & 3;
    const float* xr = xp + (size_t)n * HH + hh * DH;
    float s1 = 0.f, s2 = 0.f;
#pragma unroll
    for (int d = 0; d < DH; ++d) {
        float v = xr[d];
        s1 += v * asrc[hh * DH + d];
        s2 += v * adst[hh * DH + d];
    }
    als[t] = s1;
    ald[t] = s2;
}

// ---------------- GAT per-node softmax + aggregation ----------------
__global__ __launch_bounds__(128) void k_gat_node(const int* __restrict__ esrc, const int* __restrict__ rowstart,
                                                  const int* __restrict__ cnt, const float* __restrict__ als,
                                                  const float* __restrict__ ald, const float* __restrict__ xp,
                                                  float* __restrict__ gatout) {
    int n = blockIdx.x, t = threadIdx.x;
    int base = rowstart[n], c = cnt[n];
    float4 adv = ((const float4*)ald)[n];
    float ad[4] = {adv.x, adv.y, adv.z, adv.w};
    __shared__ float red[512];
    float mx[4] = {-INFINITY, -INFINITY, -INFINITY, -INFINITY};
    for (int i = t; i < c; i += 128) {
        int s = esrc[base + i];
        float4 as = ((const float4*)als)[s];
        float lg;
        lg = as.x + ad[0]; lg = lg >= 0.f ? lg : 0.2f * lg; mx[0] = fmaxf(mx[0], lg);
        lg = as.y + ad[1]; lg = lg >= 0.f ? lg : 0.2f * lg; mx[1] = fmaxf(mx[1], lg);
        lg = as.z + ad[2]; lg = lg >= 0.f ? lg : 0.2f * lg; mx[2] = fmaxf(mx[2], lg);
        lg = as.w + ad[3]; lg = lg >= 0.f ? lg : 0.2f * lg; mx[3] = fmaxf(mx[3], lg);
    }
#pragma unroll
    for (int h = 0; h < 4; ++h) red[h * 128 + t] = mx[h];
    __syncthreads();
    for (int s2 = 64; s2 > 0; s2 >>= 1) {
        if (t < s2) {
#pragma unroll
            for (int h = 0; h < 4; ++h)
                red[h * 128 + t] = fmaxf(red[h * 128 + t], red[h * 128 + t + s2]);
        }
        __syncthreads();
    }
    float m4[4];
#pragma unroll
    for (int h = 0; h < 4; ++h) m4[h] = red[h * 128];
    __syncthreads();
    float sm[4] = {0.f, 0.f, 0.f, 0.f};
    for (int i = t; i < c; i += 128) {
        int s = esrc[base + i];
        float4 as = ((const float4*)als)[s];
        float lg;
        lg = as.x + ad[0]; lg = lg >= 0.f ? lg : 0.2f * lg; sm[0] += __expf(lg - m4[0]);
        lg = as.y + ad[1]; lg = lg >= 0.f ? lg : 0.2f * lg; sm[1] += __expf(lg - m4[1]);
        lg = as.z + ad[2]; lg = lg >= 0.f ? lg : 0.2f * lg; sm[2] += __expf(lg - m4[2]);
        lg = as.w + ad[3]; lg = lg >= 0.f ? lg : 0.2f * lg; sm[3] += __expf(lg - m4[3]);
    }
#pragma unroll
    for (int h = 0; h < 4; ++h) red[h * 128 + t] = sm[h];
    __syncthreads();
    for (int s2 = 64; s2 > 0; s2 >>= 1) {
        if (t < s2) {
#pragma unroll
            for (int h = 0; h < 4; ++h)
                red[h * 128 + t] += red[h * 128 + t + s2];
        }
        __syncthreads();
    }
    float inv[4];
#pragma unroll
    for (int h = 0; h < 4; ++h) inv[h] = 1.f / (red[h * 128] + 1e-16f);
    int ht = t >> 5;
    float mloc = m4[ht], invloc = inv[ht], adloc = ad[ht];
    float acc = 0.f;
    for (int i = 0; i < c; ++i) {
        int s = esrc[base + i];
        float lg = als[s * 4 + ht] + adloc;
        lg = lg >= 0.f ? lg : 0.2f * lg;
        float alpha = __expf(lg - mloc) * invloc;
        acc += alpha * xp[(size_t)s * HH + t];
    }
    gatout[(size_t)n * HH + t] = acc;
}

// ---------------- MHA flash with bf16 MFMA ----------------
// block = 128 threads (2 waves), each wave owns 16 Q rows of one head.
// grid = (NN/32) * HEADS = 512 blocks.
#define MHA_SCALE 0.17677669529663687f
__global__ __launch_bounds__(128) void k_mha_mfma(const u16* __restrict__ qkvb, float* __restrict__ out) {
    int head = blockIdx.x & 3;
    int qt = blockIdx.x >> 2;
    int tid = threadIdx.x;
    int wave = tid >> 6, lane = tid & 63;
    int grp = lane >> 4, lcol = lane & 15;

    __shared__ __align__(16) u16 Klds[64][40];      // [key][dim] pad->40
    __shared__ __align__(16) u16 Vlds[32][72];      // [dim][key] pad->72
    __shared__ __align__(16) u16 Plds[2][16][72];   // per-wave [row][key] pad->72

    int qrow0 = qt * 32 + wave * 16;
    // Q A-fragment: A[m=lcol][k=grp*8+j]
    bf16x8 aQ = *(const bf16x8*)(qkvb + (size_t)(qrow0 + lcol) * 384 + head * 32 + grp * 8);

    f32x4 oc0 = {0.f, 0.f, 0.f, 0.f}, oc1 = {0.f, 0.f, 0.f, 0.f};
    float mrow[4] = {-INFINITY, -INFINITY, -INFINITY, -INFINITY};
    float lrow[4] = {0.f, 0.f, 0.f, 0.f};

    int skey = tid >> 1;              // 0..63
    int shalf = (tid & 1) * 16;       // dim offset 0/16
    const u16* kvsrc = qkvb + 128 + head * 32 + shalf;

    for (int kt = 0; kt < NN; kt += 64) {
        __syncthreads();
        const u16* kp = kvsrc + (size_t)(kt + skey) * 384;
        bf16x8 k0 = *(const bf16x8*)kp;
        bf16x8 k1 = *(const bf16x8*)(kp + 8);
        bf16x8 v0 = *(const bf16x8*)(kp + 128);
        bf16x8 v1 = *(const bf16x8*)(kp + 136);
        *(bf16x8*)(&Klds[skey][shalf]) = k0;
        *(bf16x8*)(&Klds[skey][shalf + 8]) = k1;
#pragma unroll
        for (int j = 0; j < 8; ++j) {
            Vlds[shalf + j][skey] = (u16)v0[j];
            Vlds[shalf + 8 + j][skey] = (u16)v1[j];
        }
        __syncthreads();

        // scores: 4 sub-tiles of 16 keys; B[k=dim][n=key] from Klds
        f32x4 sc[4];
        f32x4 zero = {0.f, 0.f, 0.f, 0.f};
#pragma unroll
        for (int s = 0; s < 4; ++s) {
            bf16x8 bK = *(const bf16x8*)(&Klds[s * 16 + lcol][grp * 8]);
            sc[s] = __builtin_amdgcn_mfma_f32_16x16x32_bf16(aQ, bK, zero, 0, 0, 0);
        }
        // online softmax per C-reg r (row = grp*4+r, 16 lanes share a row-group)
#pragma unroll
        for (int r = 0; r < 4; ++r) {
            float s0 = sc[0][r] * MHA_SCALE, s1 = sc[1][r] * MHA_SCALE;
            float s2 = sc[2][r] * MHA_SCALE, s3 = sc[3][r] * MHA_SCALE;
            float mx = fmaxf(fmaxf(s0, s1), fmaxf(s2, s3));
            mx = fmaxf(mx, __shfl_xor(mx, 1));
            mx = fmaxf(mx, __shfl_xor(mx, 2));
            mx = fmaxf(mx, __shfl_xor(mx, 4));
            mx = fmaxf(mx, __shfl_xor(mx, 8));
            float mnew = fmaxf(mrow[r], mx);
            float c = __expf(mrow[r] - mnew);
            float p0 = __expf(s0 - mnew), p1 = __expf(s1 - mnew);
            float p2 = __expf(s2 - mnew), p3 = __expf(s3 - mnew);
            float sum = (p0 + p1) + (p2 + p3);
            sum += __shfl_xor(sum, 1);
            sum += __shfl_xor(sum, 2);
            sum += __shfl_xor(sum, 4);
            sum += __shfl_xor(sum, 8);
            lrow[r] = lrow[r] * c + sum;
            mrow[r] = mnew;
            int prow = grp * 4 + r;
            Plds[wave][prow][0 * 16 + lcol] = (u16)(__float_as_uint(p0) >> 16);
            Plds[wave][prow][1 * 16 + lcol] = (u16)(__float_as_uint(p1) >> 16);
            Plds[wave][prow][2 * 16 + lcol] = (u16)(__float_as_uint(p2) >> 16);
            Plds[wave][prow][3 * 16 + lcol] = (u16)(__float_as_uint(p3) >> 16);
            oc0[r] *= c;
            oc1[r] *= c;
        }
        // PV: A[m=lcol][k] from Plds, B[k=key][n=dim] from Vlds (dim-major)
#pragma unroll
        for (int c2 = 0; c2 < 2; ++c2) {
            bf16x8 aP = *(const bf16x8*)(&Plds[wave][lcol][c2 * 32 + grp * 8]);
            bf16x8 bV0 = *(const bf16x8*)(&Vlds[lcol][c2 * 32 + grp * 8]);
            bf16x8 bV1 = *(const bf16x8*)(&Vlds[16 + lcol][c2 * 32 + grp * 8]);
            oc0 = __builtin_amdgcn_mfma_f32_16x16x32_bf16(aP, bV0, oc0, 0, 0, 0);
            oc1 = __builtin_amdgcn_mfma_f32_16x16x32_bf16(aP, bV1, oc1, 0, 0, 0);
        }
    }
#pragma unroll
    for (int r = 0; r < 4; ++r) {
        float inv = 1.f / lrow[r];
        int row = qrow0 + grp * 4 + r;
        out[(size_t)row * HH + head * 32 + lcol] = oc0[r] * inv;
        out[(size_t)row * HH + head * 32 + 16 + lcol] = oc1[r] * inv;
    }
}

// ---------------- elementwise combine / final ----------------
__global__ void k_combine(const float* __restrict__ gat, const float* __restrict__ proj,
                          const float* __restrict__ h, const float* __restrict__ bgat,
                          const float* __restrict__ gam, const float* __restrict__ bet,
                          float* __restrict__ outb) {
    int t = blockIdx.x * blockDim.x + threadIdx.x;
    if (t >= NN * HH) return;
    int j = t & (HH - 1);
    float rs = rsqrtf(1.00001f);
    float g0 = gam[j] * rs, b0 = bet[j];
    float g1 = gam[HH + j] * rs, b1 = bet[HH + j];
    float hv = h[t];
    float hl = g0 * (gat[t] + bgat[j] + hv) + b0;
    float ha = g1 * (proj[t] + hv) + b1;
    outb[t] = hl + ha;
}

__global__ void k_final(const float* __restrict__ outb, const float* __restrict__ mlpo,
                        const float* __restrict__ gam, const float* __restrict__ bet,
                        float* __restrict__ h) {
    int t = blockIdx.x * blockDim.x + threadIdx.x;
    if (t >= NN * HH) return;
    int j = t & (HH - 1);
    float rs = rsqrtf(1.00001f);
    float g2 = gam[2 * HH + j] * rs, b2 = bet[2 * HH + j];
    float o2 = g2 * (outb[t] + mlpo[t]) + b2;
    h[t] = fmaxf(o2 + h[t], 0.f);
}

// ---------------- output projection (dtype-adaptive store) ----------------
__global__ __launch_bounds__(64) void k_out(const float* __restrict__ h, const float* __restrict__ w,
                                            const float* __restrict__ b, void* __restrict__ yout,
                                            const int* __restrict__ flag) {
    int n = blockIdx.x, l = threadIdx.x;
    float a0 = 0.f, a1 = 0.f;
    for (int k = l; k < HH; k += 64) {
        float hv = h[(size_t)n * HH + k];
        a0 += hv * w[k];
        a1 += hv * w[HH + k];
    }
#pragma unroll
    for (int off = 32; off > 0; off >>= 1) {
        a0 += __shfl_xor(a0, off);
        a1 += __shfl_xor(a1, off);
    }
    if (l == 0) {
        float o0 = a0 + b[0], o1 = a1 + b[1];
        if (*flag) {
            u16* y = (u16*)yout;
            y[n * 2 + 0] = f2bf(o0);
            y[n * 2 + 1] = f2bf(o1);
        } else {
            float* y = (float*)yout;
            y[n * 2 + 0] = o0;
            y[n * 2 + 1] = o1;
        }
    }
}

extern "C" void kernel_launch(void* const* d_in, const int* in_sizes, int n_in,
                              void* d_out, int out_size, void* d_ws, size_t ws_size,
                              hipStream_t stream) {
    float* W = (float*)d_ws;
    size_t o = 0;
    auto take = [&](size_t n) { size_t r = o; o += n; return r; };
    size_t px    = take(NN * INF_);
    size_t pw_in = take(HH * INF_);
    size_t pb_in = take(HH);
    size_t pw_gat = take(LL * HH * HH);
    size_t pattS  = take(LL * HEADS * DH);
    size_t pattD  = take(LL * HEADS * DH);
    size_t pb_gat = take(LL * HH);
    size_t pw_qkv = take(LL * 3 * HH * HH);
    size_t pb_qkv = take(LL * 3 * HH);
    size_t pw_o   = take(LL * HH * HH);
    size_t pb_o   = take(LL * HH);
    size_t pbn_g  = take(LL * 3 * HH);
    size_t pbn_b  = take(LL * 3 * HH);
    size_t pw1    = take(LL * 2 * HH * HH);
    size_t pb1    = take(LL * 2 * HH);
    size_t pw2    = take(LL * HH * 2 * HH);
    size_t pb2    = take(LL * HH);
    size_t pw_out = take(2 * HH);
    size_t pb_out = take(2);
    o = (o + 127) & ~(size_t)127;
    size_t ohbuf = take(NH);
    size_t ogat  = take(NH);
    size_t obig  = take(3 * NH);
    size_t otmp  = take(NH);
    size_t oals  = take(NN * HEADS);
    size_t oald  = take(NN * HEADS);
    size_t oqkvb = take(NN * 192);   // NN*384 u16
    int* ibase    = (int*)(W + o);
    int* iflag    = ibase;
    int* cnt      = ibase + 64;
    int* rowstart = cnt + NN;
    int* cursor   = rowstart + NN;
    int* esrc     = cursor + NN;

    float* hbuf = W + ohbuf;
    float* gatb = W + ogat;
    float* big  = W + obig;
    float* tmp  = W + otmp;
    float* als  = W + oals;
    float* ald  = W + oald;
    u16* qkvb   = (u16*)(W + oqkvb);

    const int* src = (const int*)d_in[1];
    const int* dst = (const int*)d_in[1] + EE;

    k_detect<<<1, 256, 0, stream>>>((const u16*)d_in[0], iflag);
    struct { int idx; size_t off; int n; } cv[] = {
        {0,  px,    NN * INF_},      {2,  pw_in, HH * INF_},     {3,  pb_in, HH},
        {4,  pw_gat, LL * HH * HH},  {5,  pattS, LL * HEADS * DH},
        {6,  pattD, LL * HEADS * DH},{7,  pb_gat, LL * HH},
        {8,  pw_qkv, LL * 3 * HH * HH}, {9, pb_qkv, LL * 3 * HH},
        {10, pw_o,  LL * HH * HH},   {11, pb_o,  LL * HH},
        {12, pbn_g, LL * 3 * HH},    {13, pbn_b, LL * 3 * HH},
        {14, pw1,   LL * 2 * HH * HH}, {15, pb1, LL * 2 * HH},
        {16, pw2,   LL * HH * 2 * HH}, {17, pb2, LL * HH},
        {18, pw_out, 2 * HH},        {19, pb_out, 2},
    };
    for (auto& c : cv)
        k_cvt<<<(c.n + 255) / 256, 256, 0, stream>>>(d_in[c.idx], W + c.off, c.n, iflag);

    k_zero<<<16, 256, 0, stream>>>(cnt);
    k_hist<<<EE / 256, 256, 0, stream>>>(dst, cnt);
    k_scan<<<1, 256, 0, stream>>>(cnt, rowstart, cursor);
    k_scatter<<<EE / 256, 256, 0, stream>>>(src, dst, cursor, esrc);

    k_in_proj<<<NN, 128, 0, stream>>>(W + px, W + pw_in, W + pb_in, hbuf);

    for (int l = 0; l < LL; ++l) {
        // GAT branch: xp -> tmp
        k_gemm<<<NN, HH, 0, stream>>>(hbuf, W + pw_gat + (size_t)l * HH * HH, nullptr, tmp, HH, 0);
        k_attlog<<<(NN * HEADS) / 256, 256, 0, stream>>>(tmp, W + pattS + l * HEADS * DH,
                                                         W + pattD + l * HEADS * DH, als, ald);
        k_gat_node<<<NN, 128, 0, stream>>>(esrc, rowstart, cnt, als, ald, tmp, gatb);
        // MHA branch: qkv f32 -> big; bf16 copy -> qkvb; flash MFMA -> tmp; w_o -> big
        k_gemm<<<NN, 3 * HH, 0, stream>>>(hbuf, W + pw_qkv + (size_t)l * 3 * HH * HH,
                                          W + pb_qkv + l * 3 * HH, big, HH, 0);
        k_f2b<<<(NN * 384) / 256, 256, 0, stream>>>(big, qkvb, NN * 384);
        k_mha_mfma<<<(NN / 32) * HEADS, 128, 0, stream>>>(qkvb, tmp);
        k_gemm<<<NN, HH, 0, stream>>>(tmp, W + pw_o + (size_t)l * HH * HH, W + pb_o + l * HH,
                                      big, HH, 0);
        k_combine<<<(NN * HH) / 256, 256, 0, stream>>>(gatb, big, hbuf, W + pb_gat + l * HH,
                                                       W + pbn_g + l * 3 * HH, W + pbn_b + l * 3 * HH,
                                                       tmp);
        k_gemm<<<NN, 2 * HH, 0, stream>>>(tmp, W + pw1 + (size_t)l * 2 * HH * HH,
                                          W + pb1 + l * 2 * HH, big, HH, 1);
        k_gemm<<<NN, HH, 0, stream>>>(big, W + pw2 + (size_t)l * HH * 2 * HH, W + pb2 + l * HH,
                                      big + 2 * (size_t)NH, 2 * HH, 0);
        k_final<<<(NN * HH) / 256, 256, 0, stream>>>(tmp, big + 2 * (size_t)NH,
                                                     W + pbn_g + l * 3 * HH, W + pbn_b + l * 3 * HH,
                                                     hbuf);
    }
    k_out<<<NN, 64, 0, stream>>>(hbuf, W + pw_out, W + pb_out, d_out, iflag);
}

// Round 4
// 500.042 us; speedup vs baseline: 3.2072x; 1.9819x over previous
//
#include <hip/hip_runtime.h>

#define NN 4096
#define EE 262144
#define INF_ 64
#define HH 128
#define HEADS 4
#define DH 32
#define LL 2
#define NH (NN * HH)

typedef unsigned short u16;
typedef unsigned int u32;
using bf16x8 = __attribute__((ext_vector_type(8))) short;
using f32x4 = __attribute__((ext_vector_type(4))) float;

__device__ __forceinline__ float bf2f(u16 v) { return __uint_as_float(((u32)v) << 16); }
__device__ __forceinline__ u16 f2bf(float f) {
    u32 u = __float_as_uint(f);
    u32 r = (u + 0x7fffu + ((u >> 16) & 1u)) >> 16;
    return (u16)r;
}

// ---------------- dtype detect ----------------
__global__ __launch_bounds__(256) void k_detect(const u16* __restrict__ x, int* __restrict__ flag) {
    __shared__ int cs[256];
    int t = threadIdx.x;
    u16 v = x[2 * t];
    int e = (v >> 7) & 0xFF;
    cs[t] = (e >= 100 && e <= 140) ? 1 : 0;
    __syncthreads();
    for (int s = 128; s > 0; s >>= 1) {
        if (t < s) cs[t] += cs[t + s];
        __syncthreads();
    }
    if (t == 0) *flag = (cs[0] >= 128) ? 1 : 0;
}

// ---------------- batched param conversion ----------------
#define MAXSEG 16
struct SegF { const void* src[MAXSEG]; int dst[MAXSEG]; int n[MAXSEG]; int cnt; };
__global__ void k_cvtf(SegF S, float* __restrict__ W, const int* __restrict__ flag) {
    int seg = blockIdx.y;
    if (seg >= S.cnt) return;
    int n = S.n[seg];
    float* d = W + S.dst[seg];
    const void* s = S.src[seg];
    int f = *flag;
    for (int i = blockIdx.x * 256 + threadIdx.x; i < n; i += gridDim.x * 256)
        d[i] = f ? bf2f(((const u16*)s)[i]) : ((const float*)s)[i];
}
struct SegB { const void* src[8]; u16* dst[8]; int n[8]; int cnt; };
__global__ void k_cvtb(SegB S, const int* __restrict__ flag) {
    int seg = blockIdx.y;
    if (seg >= S.cnt) return;
    int n = S.n[seg];
    u16* d = S.dst[seg];
    const void* s = S.src[seg];
    int f = *flag;
    for (int i = blockIdx.x * 256 + threadIdx.x; i < n; i += gridDim.x * 256)
        d[i] = f ? ((const u16*)s)[i] : f2bf(((const float*)s)[i]);
}

__global__ void k_split(const float* __restrict__ src, u16* __restrict__ hi, u16* __restrict__ lo, int n) {
    int i = blockIdx.x * blockDim.x + threadIdx.x;
    if (i >= n) return;
    float v = src[i];
    u16 h = f2bf(v);
    hi[i] = h;
    lo[i] = f2bf(v - bf2f(h));
}

// ---------------- CSR build ----------------
__global__ void k_zero(int* cnt) {
    int t = blockIdx.x * blockDim.x + threadIdx.x;
    if (t < NN) cnt[t] = 0;
}
__global__ void k_hist(const int* __restrict__ dst, int* __restrict__ cnt) {
    int e = blockIdx.x * blockDim.x + threadIdx.x;
    if (e < EE) atomicAdd(&cnt[dst[e]], 1);
}
__global__ __launch_bounds__(256) void k_scan(const int* __restrict__ cnt, int* __restrict__ rowstart,
                                              int* __restrict__ cursor) {
    __shared__ int part[256];
    int t = threadIdx.x;
    int loc[16];
    int s = 0;
#pragma unroll
    for (int i = 0; i < 16; ++i) { loc[i] = s; s += cnt[t * 16 + i]; }
    part[t] = s;
    __syncthreads();
    for (int off = 1; off < 256; off <<= 1) {
        int v = part[t];
        int a = (t >= off) ? part[t - off] : 0;
        __syncthreads();
        part[t] = v + a;
        __syncthreads();
    }
    int base = (t == 0) ? 0 : part[t - 1];
#pragma unroll
    for (int i = 0; i < 16; ++i) {
        rowstart[t * 16 + i] = base + loc[i];
        cursor[t * 16 + i] = base + loc[i];
    }
}
__global__ void k_scatter(const int* __restrict__ src, const int* __restrict__ dst,
                          int* __restrict__ cursor, int* __restrict__ esrc) {
    int e = blockIdx.x * blockDim.x + threadIdx.x;
    if (e < EE) {
        int d = dst[e];
        int p = atomicAdd(&cursor[d], 1);
        esrc[p] = src[e];
    }
}

// ---------------- MFMA GEMM: C[M,J] = (Ahi+Alo)[M,K] * W[J,K]^T + bias ----------------
// grid = (M/64, J/64), block = 256 (4 waves, each 16 rows x 64 cols). LDS-free.
__global__ __launch_bounds__(256) void k_mgemm(const u16* __restrict__ Ahi, const u16* __restrict__ Alo,
                                               const u16* __restrict__ Wb, const float* __restrict__ bias,
                                               float* __restrict__ outf, u16* __restrict__ outb16,
                                               u16* __restrict__ outhi, u16* __restrict__ outlo,
                                               int K, int J, int relu) {
    int wave = threadIdx.x >> 6, lane = threadIdx.x & 63;
    int grp = lane >> 4, lcol = lane & 15;
    int m0 = blockIdx.x * 64 + wave * 16;
    int j0 = blockIdx.y * 64;
    f32x4 acc[4];
#pragma unroll
    for (int s = 0; s < 4; ++s) acc[s] = (f32x4){0.f, 0.f, 0.f, 0.f};
    const u16* ah = Ahi + (size_t)(m0 + lcol) * K + grp * 8;
    const u16* al = Alo + (size_t)(m0 + lcol) * K + grp * 8;
    const u16* wb = Wb + (size_t)(j0 + lcol) * K + grp * 8;
    for (int k = 0; k < K; k += 32) {
        bf16x8 va = *(const bf16x8*)(ah + k);
        bf16x8 vl = *(const bf16x8*)(al + k);
#pragma unroll
        for (int s = 0; s < 4; ++s) {
            bf16x8 vw = *(const bf16x8*)(wb + (size_t)s * 16 * K + k);
            acc[s] = __builtin_amdgcn_mfma_f32_16x16x32_bf16(va, vw, acc[s], 0, 0, 0);
            acc[s] = __builtin_amdgcn_mfma_f32_16x16x32_bf16(vl, vw, acc[s], 0, 0, 0);
        }
    }
#pragma unroll
    for (int s = 0; s < 4; ++s) {
        int col = j0 + s * 16 + lcol;
        float bs = bias ? bias[col] : 0.f;
#pragma unroll
        for (int r = 0; r < 4; ++r) {
            float v = acc[s][r] + bs;
            if (relu) v = fmaxf(v, 0.f);
            size_t idx = (size_t)(m0 + grp * 4 + r) * J + col;
            if (outf) outf[idx] = v;
            if (outb16) outb16[idx] = f2bf(v);
            if (outhi) {
                u16 hv = f2bf(v);
                outhi[idx] = hv;
                outlo[idx] = f2bf(v - bf2f(hv));
            }
        }
    }
}

__global__ void k_attlog(const float* __restrict__ xp, const float* __restrict__ asrc,
                         const float* __restrict__ adst, float* __restrict__ als, float* __restrict__ ald) {
    int t = blockIdx.x * blockDim.x + threadIdx.x;
    if (t >= NN * HEADS) return;
    int n = t >> 2, hh = t & 3;
    const float* xr = xp + (size_t)n * HH + hh * DH;
    float s1 = 0.f, s2 = 0.f;
#pragma unroll
    for (int d = 0; d < DH; ++d) {
        float v = xr[d];
        s1 += v * asrc[hh * DH + d];
        s2 += v * adst[hh * DH + d];
    }
    als[t] = s1;
    ald[t] = s2;
}

// ---------------- GAT per-node softmax + aggregation ----------------
__global__ __launch_bounds__(128) void k_gat_node(const int* __restrict__ esrc, const int* __restrict__ rowstart,
                                                  const int* __restrict__ cnt, const float* __restrict__ als,
                                                  const float* __restrict__ ald, const float* __restrict__ xp,
                                                  float* __restrict__ gatout) {
    int n = blockIdx.x, t = threadIdx.x;
    int base = rowstart[n], c = cnt[n];
    float4 adv = ((const float4*)ald)[n];
    float ad[4] = {adv.x, adv.y, adv.z, adv.w};
    __shared__ float red[512];
    float mx[4] = {-INFINITY, -INFINITY, -INFINITY, -INFINITY};
    for (int i = t; i < c; i += 128) {
        int s = esrc[base + i];
        float4 as = ((const float4*)als)[s];
        float lg;
        lg = as.x + ad[0]; lg = lg >= 0.f ? lg : 0.2f * lg; mx[0] = fmaxf(mx[0], lg);
        lg = as.y + ad[1]; lg = lg >= 0.f ? lg : 0.2f * lg; mx[1] = fmaxf(mx[1], lg);
        lg = as.z + ad[2]; lg = lg >= 0.f ? lg : 0.2f * lg; mx[2] = fmaxf(mx[2], lg);
        lg = as.w + ad[3]; lg = lg >= 0.f ? lg : 0.2f * lg; mx[3] = fmaxf(mx[3], lg);
    }
#pragma unroll
    for (int h = 0; h < 4; ++h) red[h * 128 + t] = mx[h];
    __syncthreads();
    for (int s2 = 64; s2 > 0; s2 >>= 1) {
        if (t < s2) {
#pragma unroll
            for (int h = 0; h < 4; ++h)
                red[h * 128 + t] = fmaxf(red[h * 128 + t], red[h * 128 + t + s2]);
        }
        __syncthreads();
    }
    float m4[4];
#pragma unroll
    for (int h = 0; h < 4; ++h) m4[h] = red[h * 128];
    __syncthreads();
    float sm[4] = {0.f, 0.f, 0.f, 0.f};
    for (int i = t; i < c; i += 128) {
        int s = esrc[base + i];
        float4 as = ((const float4*)als)[s];
        float lg;
        lg = as.x + ad[0]; lg = lg >= 0.f ? lg : 0.2f * lg; sm[0] += __expf(lg - m4[0]);
        lg = as.y + ad[1]; lg = lg >= 0.f ? lg : 0.2f * lg; sm[1] += __expf(lg - m4[1]);
        lg = as.z + ad[2]; lg = lg >= 0.f ? lg : 0.2f * lg; sm[2] += __expf(lg - m4[2]);
        lg = as.w + ad[3]; lg = lg >= 0.f ? lg : 0.2f * lg; sm[3] += __expf(lg - m4[3]);
    }
#pragma unroll
    for (int h = 0; h < 4; ++h) red[h * 128 + t] = sm[h];
    __syncthreads();
    for (int s2 = 64; s2 > 0; s2 >>= 1) {
        if (t < s2) {
#pragma unroll
            for (int h = 0; h < 4; ++h)
                red[h * 128 + t] += red[h * 128 + t + s2];
        }
        __syncthreads();
    }
    float inv[4];
#pragma unroll
    for (int h = 0; h < 4; ++h) inv[h] = 1.f / (red[h * 128] + 1e-16f);
    int ht = t >> 5;
    float mloc = m4[ht], invloc = inv[ht], adloc = ad[ht];
    float acc = 0.f;
    for (int i = 0; i < c; ++i) {
        int s = esrc[base + i];
        float lg = als[s * 4 + ht] + adloc;
        lg = lg >= 0.f ? lg : 0.2f * lg;
        float alpha = __expf(lg - mloc) * invloc;
        acc += alpha * xp[(size_t)s * HH + t];
    }
    gatout[(size_t)n * HH + t] = acc;
}

// ---------------- MHA flash with bf16 MFMA ----------------
#define MHA_SCALE 0.17677669529663687f
__global__ __launch_bounds__(128) void k_mha_mfma(const u16* __restrict__ qkvb,
                                                  u16* __restrict__ atthi, u16* __restrict__ attlo) {
    int head = blockIdx.x & 3;
    int qt = blockIdx.x >> 2;
    int tid = threadIdx.x;
    int wave = tid >> 6, lane = tid & 63;
    int grp = lane >> 4, lcol = lane & 15;

    __shared__ __align__(16) u16 Klds[64][40];
    __shared__ __align__(16) u16 Vlds[32][72];
    __shared__ __align__(16) u16 Plds[2][16][72];

    int qrow0 = qt * 32 + wave * 16;
    bf16x8 aQ = *(const bf16x8*)(qkvb + (size_t)(qrow0 + lcol) * 384 + head * 32 + grp * 8);

    f32x4 oc0 = {0.f, 0.f, 0.f, 0.f}, oc1 = {0.f, 0.f, 0.f, 0.f};
    float mrow[4] = {-INFINITY, -INFINITY, -INFINITY, -INFINITY};
    float lrow[4] = {0.f, 0.f, 0.f, 0.f};

    int skey = tid >> 1;
    int shalf = (tid & 1) * 16;
    const u16* kvsrc = qkvb + 128 + head * 32 + shalf;

    for (int kt = 0; kt < NN; kt += 64) {
        __syncthreads();
        const u16* kp = kvsrc + (size_t)(kt + skey) * 384;
        bf16x8 k0 = *(const bf16x8*)kp;
        bf16x8 k1 = *(const bf16x8*)(kp + 8);
        bf16x8 v0 = *(const bf16x8*)(kp + 128);
        bf16x8 v1 = *(const bf16x8*)(kp + 136);
        *(bf16x8*)(&Klds[skey][shalf]) = k0;
        *(bf16x8*)(&Klds[skey][shalf + 8]) = k1;
#pragma unroll
        for (int j = 0; j < 8; ++j) {
            Vlds[shalf + j][skey] = (u16)v0[j];
            Vlds[shalf + 8 + j][skey] = (u16)v1[j];
        }
        __syncthreads();

        f32x4 sc[4];
        f32x4 zero = {0.f, 0.f, 0.f, 0.f};
#pragma unroll
        for (int s = 0; s < 4; ++s) {
            bf16x8 bK = *(const bf16x8*)(&Klds[s * 16 + lcol][grp * 8]);
            sc[s] = __builtin_amdgcn_mfma_f32_16x16x32_bf16(aQ, bK, zero, 0, 0, 0);
        }
#pragma unroll
        for (int r = 0; r < 4; ++r) {
            float s0 = sc[0][r] * MHA_SCALE, s1 = sc[1][r] * MHA_SCALE;
            float s2 = sc[2][r] * MHA_SCALE, s3 = sc[3][r] * MHA_SCALE;
            float mx = fmaxf(fmaxf(s0, s1), fmaxf(s2, s3));
            mx = fmaxf(mx, __shfl_xor(mx, 1));
            mx = fmaxf(mx, __shfl_xor(mx, 2));
            mx = fmaxf(mx, __shfl_xor(mx, 4));
            mx = fmaxf(mx, __shfl_xor(mx, 8));
            float mnew = fmaxf(mrow[r], mx);
            float c = __expf(mrow[r] - mnew);
            float p0 = __expf(s0 - mnew), p1 = __expf(s1 - mnew);
            float p2 = __expf(s2 - mnew), p3 = __expf(s3 - mnew);
            float sum = (p0 + p1) + (p2 + p3);
            sum += __shfl_xor(sum, 1);
            sum += __shfl_xor(sum, 2);
            sum += __shfl_xor(sum, 4);
            sum += __shfl_xor(sum, 8);
            lrow[r] = lrow[r] * c + sum;
            mrow[r] = mnew;
            int prow = grp * 4 + r;
            Plds[wave][prow][0 * 16 + lcol] = (u16)(__float_as_uint(p0) >> 16);
            Plds[wave][prow][1 * 16 + lcol] = (u16)(__float_as_uint(p1) >> 16);
            Plds[wave][prow][2 * 16 + lcol] = (u16)(__float_as_uint(p2) >> 16);
            Plds[wave][prow][3 * 16 + lcol] = (u16)(__float_as_uint(p3) >> 16);
            oc0[r] *= c;
            oc1[r] *= c;
        }
#pragma unroll
        for (int c2 = 0; c2 < 2; ++c2) {
            bf16x8 aP = *(const bf16x8*)(&Plds[wave][lcol][c2 * 32 + grp * 8]);
            bf16x8 bV0 = *(const bf16x8*)(&Vlds[lcol][c2 * 32 + grp * 8]);
            bf16x8 bV1 = *(const bf16x8*)(&Vlds[16 + lcol][c2 * 32 + grp * 8]);
            oc0 = __builtin_amdgcn_mfma_f32_16x16x32_bf16(aP, bV0, oc0, 0, 0, 0);
            oc1 = __builtin_amdgcn_mfma_f32_16x16x32_bf16(aP, bV1, oc1, 0, 0, 0);
        }
    }
#pragma unroll
    for (int r = 0; r < 4; ++r) {
        float inv = 1.f / lrow[r];
        int row = qrow0 + grp * 4 + r;
        size_t i0 = (size_t)row * HH + head * 32 + lcol;
        float v0 = oc0[r] * inv, v1 = oc1[r] * inv;
        u16 h0 = f2bf(v0);
        atthi[i0] = h0;
        attlo[i0] = f2bf(v0 - bf2f(h0));
        u16 h1 = f2bf(v1);
        atthi[i0 + 16] = h1;
        attlo[i0 + 16] = f2bf(v1 - bf2f(h1));
    }
}

// ---------------- elementwise combine / final (emit hi/lo for next GEMM) ----------------
__global__ void k_combine(const float* __restrict__ gat, const float* __restrict__ proj,
                          const float* __restrict__ h, const float* __restrict__ bgat,
                          const float* __restrict__ gam, const float* __restrict__ bet,
                          float* __restrict__ outb, u16* __restrict__ ohi, u16* __restrict__ olo) {
    int t = blockIdx.x * blockDim.x + threadIdx.x;
    if (t >= NN * HH) return;
    int j = t & (HH - 1);
    float rs = rsqrtf(1.00001f);
    float g0 = gam[j] * rs, b0 = bet[j];
    float g1 = gam[HH + j] * rs, b1 = bet[HH + j];
    float hv = h[t];
    float hl = g0 * (gat[t] + bgat[j] + hv) + b0;
    float ha = g1 * (proj[t] + hv) + b1;
    float v = hl + ha;
    outb[t] = v;
    u16 hb = f2bf(v);
    ohi[t] = hb;
    olo[t] = f2bf(v - bf2f(hb));
}

__global__ void k_final(const float* __restrict__ outb, const float* __restrict__ mlpo,
                        const float* __restrict__ gam, const float* __restrict__ bet,
                        float* __restrict__ h, u16* __restrict__ hhi, u16* __restrict__ hlo) {
    int t = blockIdx.x * blockDim.x + threadIdx.x;
    if (t >= NN * HH) return;
    int j = t & (HH - 1);
    float rs = rsqrtf(1.00001f);
    float g2 = gam[2 * HH + j] * rs, b2 = bet[2 * HH + j];
    float o2 = g2 * (outb[t] + mlpo[t]) + b2;
    float v = fmaxf(o2 + h[t], 0.f);
    h[t] = v;
    u16 hb = f2bf(v);
    hhi[t] = hb;
    hlo[t] = f2bf(v - bf2f(hb));
}

// ---------------- output projection (dtype-adaptive store) ----------------
__global__ __launch_bounds__(64) void k_out(const float* __restrict__ h, const float* __restrict__ w,
                                            const float* __restrict__ b, void* __restrict__ yout,
                                            const int* __restrict__ flag) {
    int n = blockIdx.x, l = threadIdx.x;
    float a0 = 0.f, a1 = 0.f;
    for (int k = l; k < HH; k += 64) {
        float hv = h[(size_t)n * HH + k];
        a0 += hv * w[k];
        a1 += hv * w[HH + k];
    }
#pragma unroll
    for (int off = 32; off > 0; off >>= 1) {
        a0 += __shfl_xor(a0, off);
        a1 += __shfl_xor(a1, off);
    }
    if (l == 0) {
        float o0 = a0 + b[0], o1 = a1 + b[1];
        if (*flag) {
            u16* y = (u16*)yout;
            y[n * 2 + 0] = f2bf(o0);
            y[n * 2 + 1] = f2bf(o1);
        } else {
            float* y = (float*)yout;
            y[n * 2 + 0] = o0;
            y[n * 2 + 1] = o1;
        }
    }
}

extern "C" void kernel_launch(void* const* d_in, const int* in_sizes, int n_in,
                              void* d_out, int out_size, void* d_ws, size_t ws_size,
                              hipStream_t stream) {
    float* W = (float*)d_ws;
    size_t o = 0;
    auto take = [&](size_t n) { size_t r = o; o += n; return r; };
    // f32 params
    size_t px    = take(NN * INF_);
    size_t pb_in = take(HH);
    size_t pattS = take(LL * HEADS * DH);
    size_t pattD = take(LL * HEADS * DH);
    size_t pb_gat = take(LL * HH);
    size_t pb_qkv = take(LL * 3 * HH);
    size_t pb_o  = take(LL * HH);
    size_t pbn_g = take(LL * 3 * HH);
    size_t pbn_b = take(LL * 3 * HH);
    size_t pb1   = take(LL * 2 * HH);
    size_t pb2   = take(LL * HH);
    size_t pw_out = take(2 * HH);
    size_t pb_out = take(2);
    // bf16 weights (allocated in float units, used as u16*)
    auto takeb = [&](size_t nu16) { size_t r = o; o += (nu16 + 1) / 2; return r; };
    size_t bw_in  = takeb(HH * INF_);
    size_t bw_gat = takeb(LL * HH * HH);
    size_t bw_qkv = takeb(LL * 3 * HH * HH);
    size_t bw_o   = takeb(LL * HH * HH);
    size_t bw1    = takeb(LL * 2 * HH * HH);
    size_t bw2    = takeb(LL * HH * 2 * HH);
    o = (o + 127) & ~(size_t)127;
    // activation buffers
    size_t ohbuf = take(NH);
    size_t ogat  = take(NH);
    size_t obig  = take(2 * NH);      // proj f32 | mlpo f32 (reuse)
    size_t otmp  = take(NH);          // xp -> combine-out
    size_t oals  = take(NN * HEADS);
    size_t oald  = take(NN * HEADS);
    size_t oqkvb = takeb(NN * 384);
    size_t oxhi  = takeb(NN * INF_);
    size_t oxlo  = takeb(NN * INF_);
    size_t ohhi  = takeb(NH);
    size_t ohlo  = takeb(NH);
    size_t oahi  = takeb(NH);
    size_t oalo  = takeb(NH);
    size_t oohi  = takeb(NH);
    size_t oolo  = takeb(NH);
    size_t omhi  = takeb(NN * 2 * HH);
    size_t omlo  = takeb(NN * 2 * HH);
    int* ibase    = (int*)(W + o);
    int* iflag    = ibase;
    int* cnt      = ibase + 64;
    int* rowstart = cnt + NN;
    int* cursor   = rowstart + NN;
    int* esrc     = cursor + NN;

    float* hbuf = W + ohbuf;
    float* gatb = W + ogat;
    float* big  = W + obig;
    float* tmp  = W + otmp;
    float* als  = W + oals;
    float* ald  = W + oald;
    u16* qkvb = (u16*)(W + oqkvb);
    u16* xhi = (u16*)(W + oxhi), *xlo = (u16*)(W + oxlo);
    u16* hhi = (u16*)(W + ohhi), *hlo = (u16*)(W + ohlo);
    u16* ahi = (u16*)(W + oahi), *alo = (u16*)(W + oalo);
    u16* ohi = (u16*)(W + oohi), *olo = (u16*)(W + oolo);
    u16* mhi = (u16*)(W + omhi), *mlo = (u16*)(W + omlo);

    const int* src = (const int*)d_in[1];
    const int* dst = (const int*)d_in[1] + EE;

    k_detect<<<1, 256, 0, stream>>>((const u16*)d_in[0], iflag);

    // f32 param conversion (batched)
    SegF SF = {};
    int nf = 0;
    auto addf = [&](int idx, size_t off, int n) { SF.src[nf] = d_in[idx]; SF.dst[nf] = (int)off; SF.n[nf] = n; ++nf; };
    addf(0, px, NN * INF_);
    addf(3, pb_in, HH);
    addf(5, pattS, LL * HEADS * DH);
    addf(6, pattD, LL * HEADS * DH);
    addf(7, pb_gat, LL * HH);
    addf(9, pb_qkv, LL * 3 * HH);
    addf(11, pb_o, LL * HH);
    addf(12, pbn_g, LL * 3 * HH);
    addf(13, pbn_b, LL * 3 * HH);
    addf(15, pb1, LL * 2 * HH);
    addf(17, pb2, LL * HH);
    addf(18, pw_out, 2 * HH);
    addf(19, pb_out, 2);
    SF.cnt = nf;
    k_cvtf<<<dim3(128, nf), 256, 0, stream>>>(SF, W, iflag);

    // bf16 weight conversion (batched)
    SegB SB = {};
    int nb = 0;
    auto addb = [&](int idx, size_t off, int n) { SB.src[nb] = d_in[idx]; SB.dst[nb] = (u16*)(W + off); SB.n[nb] = n; ++nb; };
    addb(2, bw_in, HH * INF_);
    addb(4, bw_gat, LL * HH * HH);
    addb(8, bw_qkv, LL * 3 * HH * HH);
    addb(10, bw_o, LL * HH * HH);
    addb(14, bw1, LL * 2 * HH * HH);
    addb(16, bw2, LL * HH * 2 * HH);
    SB.cnt = nb;
    k_cvtb<<<dim3(128, nb), 256, 0, stream>>>(SB, iflag);

    k_split<<<(NN * INF_) / 256, 256, 0, stream>>>(W + px, xhi, xlo, NN * INF_);

    // CSR build
    k_zero<<<16, 256, 0, stream>>>(cnt);
    k_hist<<<EE / 256, 256, 0, stream>>>(dst, cnt);
    k_scan<<<1, 256, 0, stream>>>(cnt, rowstart, cursor);
    k_scatter<<<EE / 256, 256, 0, stream>>>(src, dst, cursor, esrc);

    // in_proj: h = relu(x @ w_in^T + b), K=64
    k_mgemm<<<dim3(NN / 64, HH / 64), 256, 0, stream>>>(xhi, xlo, (u16*)(W + bw_in), W + pb_in,
                                                        hbuf, nullptr, hhi, hlo, INF_, HH, 1);

    for (int l = 0; l < LL; ++l) {
        // GAT branch
        k_mgemm<<<dim3(NN / 64, HH / 64), 256, 0, stream>>>(hhi, hlo, (u16*)(W + bw_gat) + (size_t)l * HH * HH,
                                                            nullptr, tmp, nullptr, nullptr, nullptr, HH, HH, 0);
        k_attlog<<<(NN * HEADS) / 256, 256, 0, stream>>>(tmp, W + pattS + l * HEADS * DH,
                                                         W + pattD + l * HEADS * DH, als, ald);
        k_gat_node<<<NN, 128, 0, stream>>>(esrc, rowstart, cnt, als, ald, tmp, gatb);
        // MHA branch
        k_mgemm<<<dim3(NN / 64, 384 / 64), 256, 0, stream>>>(hhi, hlo, (u16*)(W + bw_qkv) + (size_t)l * 3 * HH * HH,
                                                             W + pb_qkv + l * 3 * HH, nullptr, qkvb,
                                                             nullptr, nullptr, HH, 3 * HH, 0);
        k_mha_mfma<<<(NN / 32) * HEADS, 128, 0, stream>>>(qkvb, ahi, alo);
        k_mgemm<<<dim3(NN / 64, HH / 64), 256, 0, stream>>>(ahi, alo, (u16*)(W + bw_o) + (size_t)l * HH * HH,
                                                            W + pb_o + l * HH, big, nullptr, nullptr, nullptr,
                                                            HH, HH, 0);
        // combine -> tmp (+hi/lo)
        k_combine<<<(NN * HH) / 256, 256, 0, stream>>>(gatb, big, hbuf, W + pb_gat + l * HH,
                                                       W + pbn_g + l * 3 * HH, W + pbn_b + l * 3 * HH,
                                                       tmp, ohi, olo);
        // MLP
        k_mgemm<<<dim3(NN / 64, 256 / 64), 256, 0, stream>>>(ohi, olo, (u16*)(W + bw1) + (size_t)l * 2 * HH * HH,
                                                             W + pb1 + l * 2 * HH, nullptr, nullptr, mhi, mlo,
                                                             HH, 2 * HH, 1);
        k_mgemm<<<dim3(NN / 64, HH / 64), 256, 0, stream>>>(mhi, mlo, (u16*)(W + bw2) + (size_t)l * HH * 2 * HH,
                                                            W + pb2 + l * HH, big, nullptr, nullptr, nullptr,
                                                            2 * HH, HH, 0);
        k_final<<<(NN * HH) / 256, 256, 0, stream>>>(tmp, big, W + pbn_g + l * 3 * HH,
                                                     W + pbn_b + l * 3 * HH, hbuf, hhi, hlo);
    }
    k_out<<<NN, 64, 0, stream>>>(hbuf, W + pw_out, W + pb_out, d_out, iflag);
}

// Round 5
// 427.435 us; speedup vs baseline: 3.7519x; 1.1699x over previous
//
#include <hip/hip_runtime.h>

#define NN 4096
#define EE 262144
#define INF_ 64
#define HH 128
#define HEADS 4
#define DH 32
#define LL 2
#define NH (NN * HH)
#define KSPLIT 4

typedef unsigned short u16;
typedef unsigned int u32;
using bf16x8 = __attribute__((ext_vector_type(8))) short;
using f32x4 = __attribute__((ext_vector_type(4))) float;

__device__ __forceinline__ float bf2f(u16 v) { return __uint_as_float(((u32)v) << 16); }
__device__ __forceinline__ u16 f2bf(float f) {
    u32 u = __float_as_uint(f);
    u32 r = (u + 0x7fffu + ((u >> 16) & 1u)) >> 16;
    return (u16)r;
}

// ---------------- dtype detect ----------------
__global__ __launch_bounds__(256) void k_detect(const u16* __restrict__ x, int* __restrict__ flag) {
    __shared__ int cs[256];
    int t = threadIdx.x;
    u16 v = x[2 * t];
    int e = (v >> 7) & 0xFF;
    cs[t] = (e >= 100 && e <= 140) ? 1 : 0;
    __syncthreads();
    for (int s = 128; s > 0; s >>= 1) {
        if (t < s) cs[t] += cs[t + s];
        __syncthreads();
    }
    if (t == 0) *flag = (cs[0] >= 128) ? 1 : 0;
}

// ---------------- batched param conversion ----------------
#define MAXSEG 16
struct SegF { const void* src[MAXSEG]; int dst[MAXSEG]; int n[MAXSEG]; int cnt; };
__global__ void k_cvtf(SegF S, float* __restrict__ W, const int* __restrict__ flag) {
    int seg = blockIdx.y;
    if (seg >= S.cnt) return;
    int n = S.n[seg];
    float* d = W + S.dst[seg];
    const void* s = S.src[seg];
    int f = *flag;
    for (int i = blockIdx.x * 256 + threadIdx.x; i < n; i += gridDim.x * 256)
        d[i] = f ? bf2f(((const u16*)s)[i]) : ((const float*)s)[i];
}
struct SegB { const void* src[8]; u16* dst[8]; int n[8]; int cnt; };
__global__ void k_cvtb(SegB S, const int* __restrict__ flag) {
    int seg = blockIdx.y;
    if (seg >= S.cnt) return;
    int n = S.n[seg];
    u16* d = S.dst[seg];
    const void* s = S.src[seg];
    int f = *flag;
    for (int i = blockIdx.x * 256 + threadIdx.x; i < n; i += gridDim.x * 256)
        d[i] = f ? ((const u16*)s)[i] : f2bf(((const float*)s)[i]);
}

__global__ void k_split(const float* __restrict__ src, u16* __restrict__ hi, u16* __restrict__ lo, int n) {
    int i = blockIdx.x * blockDim.x + threadIdx.x;
    if (i >= n) return;
    float v = src[i];
    u16 h = f2bf(v);
    hi[i] = h;
    lo[i] = f2bf(v - bf2f(h));
}

// ---------------- CSR build ----------------
__global__ void k_zero(int* cnt) {
    int t = blockIdx.x * blockDim.x + threadIdx.x;
    if (t < NN) cnt[t] = 0;
}
__global__ void k_hist(const int* __restrict__ dst, int* __restrict__ cnt) {
    int e = blockIdx.x * blockDim.x + threadIdx.x;
    if (e < EE) atomicAdd(&cnt[dst[e]], 1);
}
__global__ __launch_bounds__(256) void k_scan(const int* __restrict__ cnt, int* __restrict__ rowstart,
                                              int* __restrict__ cursor) {
    __shared__ int part[256];
    int t = threadIdx.x;
    int loc[16];
    int s = 0;
#pragma unroll
    for (int i = 0; i < 16; ++i) { loc[i] = s; s += cnt[t * 16 + i]; }
    part[t] = s;
    __syncthreads();
    for (int off = 1; off < 256; off <<= 1) {
        int v = part[t];
        int a = (t >= off) ? part[t - off] : 0;
        __syncthreads();
        part[t] = v + a;
        __syncthreads();
    }
    int base = (t == 0) ? 0 : part[t - 1];
#pragma unroll
    for (int i = 0; i < 16; ++i) {
        rowstart[t * 16 + i] = base + loc[i];
        cursor[t * 16 + i] = base + loc[i];
    }
}
__global__ void k_scatter(const int* __restrict__ src, const int* __restrict__ dst,
                          int* __restrict__ cursor, int* __restrict__ esrc) {
    int e = blockIdx.x * blockDim.x + threadIdx.x;
    if (e < EE) {
        int d = dst[e];
        int p = atomicAdd(&cursor[d], 1);
        esrc[p] = src[e];
    }
}

// ---------------- MFMA GEMM: C[M,J] = (Ahi+Alo)[M,K] * W[J,K]^T + bias ----------------
__global__ __launch_bounds__(256) void k_mgemm(const u16* __restrict__ Ahi, const u16* __restrict__ Alo,
                                               const u16* __restrict__ Wb, const float* __restrict__ bias,
                                               float* __restrict__ outf, u16* __restrict__ outb16,
                                               u16* __restrict__ outhi, u16* __restrict__ outlo,
                                               int K, int J, int relu) {
    int wave = threadIdx.x >> 6, lane = threadIdx.x & 63;
    int grp = lane >> 4, lcol = lane & 15;
    int m0 = blockIdx.x * 64 + wave * 16;
    int j0 = blockIdx.y * 64;
    f32x4 acc[4];
#pragma unroll
    for (int s = 0; s < 4; ++s) acc[s] = (f32x4){0.f, 0.f, 0.f, 0.f};
    const u16* ah = Ahi + (size_t)(m0 + lcol) * K + grp * 8;
    const u16* al = Alo + (size_t)(m0 + lcol) * K + grp * 8;
    const u16* wb = Wb + (size_t)(j0 + lcol) * K + grp * 8;
    for (int k = 0; k < K; k += 32) {
        bf16x8 va = *(const bf16x8*)(ah + k);
        bf16x8 vl = *(const bf16x8*)(al + k);
#pragma unroll
        for (int s = 0; s < 4; ++s) {
            bf16x8 vw = *(const bf16x8*)(wb + (size_t)s * 16 * K + k);
            acc[s] = __builtin_amdgcn_mfma_f32_16x16x32_bf16(va, vw, acc[s], 0, 0, 0);
            acc[s] = __builtin_amdgcn_mfma_f32_16x16x32_bf16(vl, vw, acc[s], 0, 0, 0);
        }
    }
#pragma unroll
    for (int s = 0; s < 4; ++s) {
        int col = j0 + s * 16 + lcol;
        float bs = bias ? bias[col] : 0.f;
#pragma unroll
        for (int r = 0; r < 4; ++r) {
            float v = acc[s][r] + bs;
            if (relu) v = fmaxf(v, 0.f);
            size_t idx = (size_t)(m0 + grp * 4 + r) * J + col;
            if (outf) outf[idx] = v;
            if (outb16) outb16[idx] = f2bf(v);
            if (outhi) {
                u16 hv = f2bf(v);
                outhi[idx] = hv;
                outlo[idx] = f2bf(v - bf2f(hv));
            }
        }
    }
}

__global__ void k_attlog(const float* __restrict__ xp, const float* __restrict__ asrc,
                         const float* __restrict__ adst, float* __restrict__ als, float* __restrict__ ald) {
    int t = blockIdx.x * blockDim.x + threadIdx.x;
    if (t >= NN * HEADS) return;
    int n = t >> 2, hh = t & 3;
    const float* xr = xp + (size_t)n * HH + hh * DH;
    float s1 = 0.f, s2 = 0.f;
#pragma unroll
    for (int d = 0; d < DH; ++d) {
        float v = xr[d];
        s1 += v * asrc[hh * DH + d];
        s2 += v * adst[hh * DH + d];
    }
    als[t] = s1;
    ald[t] = s2;
}

// ---------------- GAT per-node softmax + aggregation ----------------
__global__ __launch_bounds__(128) void k_gat_node(const int* __restrict__ esrc, const int* __restrict__ rowstart,
                                                  const int* __restrict__ cnt, const float* __restrict__ als,
                                                  const float* __restrict__ ald, const float* __restrict__ xp,
                                                  float* __restrict__ gatout) {
    int n = blockIdx.x, t = threadIdx.x;
    int base = rowstart[n], c = cnt[n];
    float4 adv = ((const float4*)ald)[n];
    float ad[4] = {adv.x, adv.y, adv.z, adv.w};
    __shared__ float red[512];
    float mx[4] = {-INFINITY, -INFINITY, -INFINITY, -INFINITY};
    for (int i = t; i < c; i += 128) {
        int s = esrc[base + i];
        float4 as = ((const float4*)als)[s];
        float lg;
        lg = as.x + ad[0]; lg = lg >= 0.f ? lg : 0.2f * lg; mx[0] = fmaxf(mx[0], lg);
        lg = as.y + ad[1]; lg = lg >= 0.f ? lg : 0.2f * lg; mx[1] = fmaxf(mx[1], lg);
        lg = as.z + ad[2]; lg = lg >= 0.f ? lg : 0.2f * lg; mx[2] = fmaxf(mx[2], lg);
        lg = as.w + ad[3]; lg = lg >= 0.f ? lg : 0.2f * lg; mx[3] = fmaxf(mx[3], lg);
    }
#pragma unroll
    for (int h = 0; h < 4; ++h) red[h * 128 + t] = mx[h];
    __syncthreads();
    for (int s2 = 64; s2 > 0; s2 >>= 1) {
        if (t < s2) {
#pragma unroll
            for (int h = 0; h < 4; ++h)
                red[h * 128 + t] = fmaxf(red[h * 128 + t], red[h * 128 + t + s2]);
        }
        __syncthreads();
    }
    float m4[4];
#pragma unroll
    for (int h = 0; h < 4; ++h) m4[h] = red[h * 128];
    __syncthreads();
    float sm[4] = {0.f, 0.f, 0.f, 0.f};
    for (int i = t; i < c; i += 128) {
        int s = esrc[base + i];
        float4 as = ((const float4*)als)[s];
        float lg;
        lg = as.x + ad[0]; lg = lg >= 0.f ? lg : 0.2f * lg; sm[0] += __expf(lg - m4[0]);
        lg = as.y + ad[1]; lg = lg >= 0.f ? lg : 0.2f * lg; sm[1] += __expf(lg - m4[1]);
        lg = as.z + ad[2]; lg = lg >= 0.f ? lg : 0.2f * lg; sm[2] += __expf(lg - m4[2]);
        lg = as.w + ad[3]; lg = lg >= 0.f ? lg : 0.2f * lg; sm[3] += __expf(lg - m4[3]);
    }
#pragma unroll
    for (int h = 0; h < 4; ++h) red[h * 128 + t] = sm[h];
    __syncthreads();
    for (int s2 = 64; s2 > 0; s2 >>= 1) {
        if (t < s2) {
#pragma unroll
            for (int h = 0; h < 4; ++h)
                red[h * 128 + t] += red[h * 128 + t + s2];
        }
        __syncthreads();
    }
    float inv[4];
#pragma unroll
    for (int h = 0; h < 4; ++h) inv[h] = 1.f / (red[h * 128] + 1e-16f);
    int ht = t >> 5;
    float mloc = m4[ht], invloc = inv[ht], adloc = ad[ht];
    float acc = 0.f;
    for (int i = 0; i < c; ++i) {
        int s = esrc[base + i];
        float lg = als[s * 4 + ht] + adloc;
        lg = lg >= 0.f ? lg : 0.2f * lg;
        float alpha = __expf(lg - mloc) * invloc;
        acc += alpha * xp[(size_t)s * HH + t];
    }
    gatout[(size_t)n * HH + t] = acc;
}

// ---------------- MHA flash, K-split + register prefetch + packed V staging ----------------
#define MHA_SCALE 0.17677669529663687f
__global__ __launch_bounds__(128) void k_mha_split(const u16* __restrict__ qkvb,
                                                   float* __restrict__ PM, float* __restrict__ PL,
                                                   float* __restrict__ PO) {
    int head = blockIdx.x & 3;
    int qt = (blockIdx.x >> 2) & 127;
    int ks = blockIdx.x >> 9;
    int tid = threadIdx.x;
    int wave = tid >> 6, lane = tid & 63;
    int grp = lane >> 4, lcol = lane & 15;

    __shared__ __align__(16) u16 Klds[64][40];     // [key][dim] pad 40
    __shared__ __align__(16) u32 Vlds[32][36];     // [dim][keypair] packed u32, pad 36
    __shared__ __align__(16) u16 Plds[2][16][72];  // per-wave [row][key] pad 72

    int qrow0 = qt * 32 + wave * 16;
    bf16x8 aQ = *(const bf16x8*)(qkvb + (size_t)(qrow0 + lcol) * 384 + head * 32 + grp * 8);

    f32x4 oc0 = {0.f, 0.f, 0.f, 0.f}, oc1 = {0.f, 0.f, 0.f, 0.f};
    float mrow[4] = {-INFINITY, -INFINITY, -INFINITY, -INFINITY};
    float lrow[4] = {0.f, 0.f, 0.f, 0.f};

    int skey = tid >> 1, shalf = (tid & 1) * 16;   // K staging map
    int kp = tid & 31, dgrp = tid >> 5;            // V staging map (keypair, dim-group)
    const u16* kbase = qkvb + 128 + head * 32 + shalf;
    const u16* vbase = qkvb + 256 + head * 32 + dgrp * 8;

    int kt0 = ks * (NN / KSPLIT);
    bf16x8 rk0 = *(const bf16x8*)(kbase + (size_t)(kt0 + skey) * 384);
    bf16x8 rk1 = *(const bf16x8*)(kbase + (size_t)(kt0 + skey) * 384 + 8);
    bf16x8 rv0 = *(const bf16x8*)(vbase + (size_t)(kt0 + 2 * kp) * 384);
    bf16x8 rv1 = *(const bf16x8*)(vbase + (size_t)(kt0 + 2 * kp + 1) * 384);

    const int NT = (NN / KSPLIT) / 64;
    for (int t = 0; t < NT; ++t) {
        *(bf16x8*)(&Klds[skey][shalf]) = rk0;
        *(bf16x8*)(&Klds[skey][shalf + 8]) = rk1;
#pragma unroll
        for (int j = 0; j < 8; ++j)
            Vlds[dgrp * 8 + j][kp] = (u32)(u16)rv0[j] | ((u32)(u16)rv1[j] << 16);
        __syncthreads();
        if (t + 1 < NT) {
            int kn = kt0 + (t + 1) * 64;
            rk0 = *(const bf16x8*)(kbase + (size_t)(kn + skey) * 384);
            rk1 = *(const bf16x8*)(kbase + (size_t)(kn + skey) * 384 + 8);
            rv0 = *(const bf16x8*)(vbase + (size_t)(kn + 2 * kp) * 384);
            rv1 = *(const bf16x8*)(vbase + (size_t)(kn + 2 * kp + 1) * 384);
        }
        f32x4 sc[4];
        f32x4 zero = {0.f, 0.f, 0.f, 0.f};
#pragma unroll
        for (int s = 0; s < 4; ++s) {
            bf16x8 bK = *(const bf16x8*)(&Klds[s * 16 + lcol][grp * 8]);
            sc[s] = __builtin_amdgcn_mfma_f32_16x16x32_bf16(aQ, bK, zero, 0, 0, 0);
        }
#pragma unroll
        for (int r = 0; r < 4; ++r) {
            float s0 = sc[0][r] * MHA_SCALE, s1 = sc[1][r] * MHA_SCALE;
            float s2 = sc[2][r] * MHA_SCALE, s3 = sc[3][r] * MHA_SCALE;
            float mx = fmaxf(fmaxf(s0, s1), fmaxf(s2, s3));
            mx = fmaxf(mx, __shfl_xor(mx, 1));
            mx = fmaxf(mx, __shfl_xor(mx, 2));
            mx = fmaxf(mx, __shfl_xor(mx, 4));
            mx = fmaxf(mx, __shfl_xor(mx, 8));
            float mnew = fmaxf(mrow[r], mx);
            float c = __expf(mrow[r] - mnew);
            float p0 = __expf(s0 - mnew), p1 = __expf(s1 - mnew);
            float p2 = __expf(s2 - mnew), p3 = __expf(s3 - mnew);
            float sum = (p0 + p1) + (p2 + p3);
            sum += __shfl_xor(sum, 1);
            sum += __shfl_xor(sum, 2);
            sum += __shfl_xor(sum, 4);
            sum += __shfl_xor(sum, 8);
            lrow[r] = lrow[r] * c + sum;
            mrow[r] = mnew;
            int prow = grp * 4 + r;
            Plds[wave][prow][0 * 16 + lcol] = (u16)(__float_as_uint(p0) >> 16);
            Plds[wave][prow][1 * 16 + lcol] = (u16)(__float_as_uint(p1) >> 16);
            Plds[wave][prow][2 * 16 + lcol] = (u16)(__float_as_uint(p2) >> 16);
            Plds[wave][prow][3 * 16 + lcol] = (u16)(__float_as_uint(p3) >> 16);
            oc0[r] *= c;
            oc1[r] *= c;
        }
#pragma unroll
        for (int c2 = 0; c2 < 2; ++c2) {
            bf16x8 aP = *(const bf16x8*)(&Plds[wave][lcol][c2 * 32 + grp * 8]);
            bf16x8 bV0 = *(const bf16x8*)(&Vlds[lcol][c2 * 16 + grp * 4]);
            bf16x8 bV1 = *(const bf16x8*)(&Vlds[16 + lcol][c2 * 16 + grp * 4]);
            oc0 = __builtin_amdgcn_mfma_f32_16x16x32_bf16(aP, bV0, oc0, 0, 0, 0);
            oc1 = __builtin_amdgcn_mfma_f32_16x16x32_bf16(aP, bV1, oc1, 0, 0, 0);
        }
        __syncthreads();
    }
#pragma unroll
    for (int r = 0; r < 4; ++r) {
        int row = qrow0 + grp * 4 + r;
        size_t base = ((size_t)row * HEADS + head) * KSPLIT + ks;
        PO[base * 32 + lcol] = oc0[r];
        PO[base * 32 + 16 + lcol] = oc1[r];
        if (lcol == 0) {
            PM[base] = mrow[r];
            PL[base] = lrow[r];
        }
    }
}

__global__ void k_mha_comb(const float* __restrict__ PM, const float* __restrict__ PL,
                           const float* __restrict__ PO, u16* __restrict__ atthi,
                           u16* __restrict__ attlo) {
    int t = blockIdx.x * 256 + threadIdx.x;
    if (t >= NN * HH) return;
    int row = t >> 7, col = t & 127;
    int head = col >> 5, dim = col & 31;
    size_t b0 = ((size_t)row * HEADS + head) * KSPLIT;
    float m = fmaxf(fmaxf(PM[b0], PM[b0 + 1]), fmaxf(PM[b0 + 2], PM[b0 + 3]));
    float l = 0.f, o = 0.f;
#pragma unroll
    for (int k = 0; k < KSPLIT; ++k) {
        float w = __expf(PM[b0 + k] - m);
        l += PL[b0 + k] * w;
        o += PO[(b0 + k) * 32 + dim] * w;
    }
    float v = o / l;
    u16 h = f2bf(v);
    atthi[t] = h;
    attlo[t] = f2bf(v - bf2f(h));
}

// ---------------- elementwise combine / final ----------------
__global__ void k_combine(const float* __restrict__ gat, const float* __restrict__ proj,
                          const float* __restrict__ h, const float* __restrict__ bgat,
                          const float* __restrict__ gam, const float* __restrict__ bet,
                          float* __restrict__ outb, u16* __restrict__ ohi, u16* __restrict__ olo) {
    int t = blockIdx.x * blockDim.x + threadIdx.x;
    if (t >= NN * HH) return;
    int j = t & (HH - 1);
    float rs = rsqrtf(1.00001f);
    float g0 = gam[j] * rs, b0 = bet[j];
    float g1 = gam[HH + j] * rs, b1 = bet[HH + j];
    float hv = h[t];
    float hl = g0 * (gat[t] + bgat[j] + hv) + b0;
    float ha = g1 * (proj[t] + hv) + b1;
    float v = hl + ha;
    outb[t] = v;
    u16 hb = f2bf(v);
    ohi[t] = hb;
    olo[t] = f2bf(v - bf2f(hb));
}

__global__ void k_final(const float* __restrict__ outb, const float* __restrict__ mlpo,
                        const float* __restrict__ gam, const float* __restrict__ bet,
                        float* __restrict__ h, u16* __restrict__ hhi, u16* __restrict__ hlo) {
    int t = blockIdx.x * blockDim.x + threadIdx.x;
    if (t >= NN * HH) return;
    int j = t & (HH - 1);
    float rs = rsqrtf(1.00001f);
    float g2 = gam[2 * HH + j] * rs, b2 = bet[2 * HH + j];
    float o2 = g2 * (outb[t] + mlpo[t]) + b2;
    float v = fmaxf(o2 + h[t], 0.f);
    h[t] = v;
    u16 hb = f2bf(v);
    hhi[t] = hb;
    hlo[t] = f2bf(v - bf2f(hb));
}

// ---------------- output projection ----------------
__global__ __launch_bounds__(64) void k_out(const float* __restrict__ h, const float* __restrict__ w,
                                            const float* __restrict__ b, void* __restrict__ yout,
                                            const int* __restrict__ flag) {
    int n = blockIdx.x, l = threadIdx.x;
    float a0 = 0.f, a1 = 0.f;
    for (int k = l; k < HH; k += 64) {
        float hv = h[(size_t)n * HH + k];
        a0 += hv * w[k];
        a1 += hv * w[HH + k];
    }
#pragma unroll
    for (int off = 32; off > 0; off >>= 1) {
        a0 += __shfl_xor(a0, off);
        a1 += __shfl_xor(a1, off);
    }
    if (l == 0) {
        float o0 = a0 + b[0], o1 = a1 + b[1];
        if (*flag) {
            u16* y = (u16*)yout;
            y[n * 2 + 0] = f2bf(o0);
            y[n * 2 + 1] = f2bf(o1);
        } else {
            float* y = (float*)yout;
            y[n * 2 + 0] = o0;
            y[n * 2 + 1] = o1;
        }
    }
}

extern "C" void kernel_launch(void* const* d_in, const int* in_sizes, int n_in,
                              void* d_out, int out_size, void* d_ws, size_t ws_size,
                              hipStream_t stream) {
    float* W = (float*)d_ws;
    size_t o = 0;
    auto take = [&](size_t n) { size_t r = o; o += n; return r; };
    size_t px    = take(NN * INF_);
    size_t pb_in = take(HH);
    size_t pattS = take(LL * HEADS * DH);
    size_t pattD = take(LL * HEADS * DH);
    size_t pb_gat = take(LL * HH);
    size_t pb_qkv = take(LL * 3 * HH);
    size_t pb_o  = take(LL * HH);
    size_t pbn_g = take(LL * 3 * HH);
    size_t pbn_b = take(LL * 3 * HH);
    size_t pb1   = take(LL * 2 * HH);
    size_t pb2   = take(LL * HH);
    size_t pw_out = take(2 * HH);
    size_t pb_out = take(2);
    auto takeb = [&](size_t nu16) { size_t r = o; o += (nu16 + 1) / 2; return r; };
    size_t bw_in  = takeb(HH * INF_);
    size_t bw_gat = takeb(LL * HH * HH);
    size_t bw_qkv = takeb(LL * 3 * HH * HH);
    size_t bw_o   = takeb(LL * HH * HH);
    size_t bw1    = takeb(LL * 2 * HH * HH);
    size_t bw2    = takeb(LL * HH * 2 * HH);
    o = (o + 127) & ~(size_t)127;
    size_t ohbuf = take(NH);
    size_t ogat  = take(NH);
    size_t obig  = take(2 * NH);
    size_t otmp  = take(NH);
    size_t oals  = take(NN * HEADS);
    size_t oald  = take(NN * HEADS);
    size_t opm   = take(NN * HEADS * KSPLIT);
    size_t opl   = take(NN * HEADS * KSPLIT);
    size_t opo   = take((size_t)NN * HEADS * KSPLIT * 32);
    size_t oqkvb = takeb(NN * 384);
    size_t oxhi  = takeb(NN * INF_);
    size_t oxlo  = takeb(NN * INF_);
    size_t ohhi  = takeb(NH);
    size_t ohlo  = takeb(NH);
    size_t oahi  = takeb(NH);
    size_t oalo  = takeb(NH);
    size_t oohi  = takeb(NH);
    size_t oolo  = takeb(NH);
    size_t omhi  = takeb(NN * 2 * HH);
    size_t omlo  = takeb(NN * 2 * HH);
    int* ibase    = (int*)(W + o);
    int* iflag    = ibase;
    int* cnt      = ibase + 64;
    int* rowstart = cnt + NN;
    int* cursor   = rowstart + NN;
    int* esrc     = cursor + NN;

    float* hbuf = W + ohbuf;
    float* gatb = W + ogat;
    float* big  = W + obig;
    float* tmp  = W + otmp;
    float* als  = W + oals;
    float* ald  = W + oald;
    float* pmb  = W + opm;
    float* plb  = W + opl;
    float* pob  = W + opo;
    u16* qkvb = (u16*)(W + oqkvb);
    u16* xhi = (u16*)(W + oxhi), *xlo = (u16*)(W + oxlo);
    u16* hhi = (u16*)(W + ohhi), *hlo = (u16*)(W + ohlo);
    u16* ahi = (u16*)(W + oahi), *alo = (u16*)(W + oalo);
    u16* ohi = (u16*)(W + oohi), *olo = (u16*)(W + oolo);
    u16* mhi = (u16*)(W + omhi), *mlo = (u16*)(W + omlo);

    const int* src = (const int*)d_in[1];
    const int* dst = (const int*)d_in[1] + EE;

    k_detect<<<1, 256, 0, stream>>>((const u16*)d_in[0], iflag);

    SegF SF = {};
    int nf = 0;
    auto addf = [&](int idx, size_t off, int n) { SF.src[nf] = d_in[idx]; SF.dst[nf] = (int)off; SF.n[nf] = n; ++nf; };
    addf(0, px, NN * INF_);
    addf(3, pb_in, HH);
    addf(5, pattS, LL * HEADS * DH);
    addf(6, pattD, LL * HEADS * DH);
    addf(7, pb_gat, LL * HH);
    addf(9, pb_qkv, LL * 3 * HH);
    addf(11, pb_o, LL * HH);
    addf(12, pbn_g, LL * 3 * HH);
    addf(13, pbn_b, LL * 3 * HH);
    addf(15, pb1, LL * 2 * HH);
    addf(17, pb2, LL * HH);
    addf(18, pw_out, 2 * HH);
    addf(19, pb_out, 2);
    SF.cnt = nf;
    k_cvtf<<<dim3(128, nf), 256, 0, stream>>>(SF, W, iflag);

    SegB SB = {};
    int nb = 0;
    auto addb = [&](int idx, size_t off, int n) { SB.src[nb] = d_in[idx]; SB.dst[nb] = (u16*)(W + off); SB.n[nb] = n; ++nb; };
    addb(2, bw_in, HH * INF_);
    addb(4, bw_gat, LL * HH * HH);
    addb(8, bw_qkv, LL * 3 * HH * HH);
    addb(10, bw_o, LL * HH * HH);
    addb(14, bw1, LL * 2 * HH * HH);
    addb(16, bw2, LL * HH * 2 * HH);
    SB.cnt = nb;
    k_cvtb<<<dim3(128, nb), 256, 0, stream>>>(SB, iflag);

    k_split<<<(NN * INF_) / 256, 256, 0, stream>>>(W + px, xhi, xlo, NN * INF_);

    k_zero<<<16, 256, 0, stream>>>(cnt);
    k_hist<<<EE / 256, 256, 0, stream>>>(dst, cnt);
    k_scan<<<1, 256, 0, stream>>>(cnt, rowstart, cursor);
    k_scatter<<<EE / 256, 256, 0, stream>>>(src, dst, cursor, esrc);

    k_mgemm<<<dim3(NN / 64, HH / 64), 256, 0, stream>>>(xhi, xlo, (u16*)(W + bw_in), W + pb_in,
                                                        hbuf, nullptr, hhi, hlo, INF_, HH, 1);

    for (int l = 0; l < LL; ++l) {
        // GAT branch
        k_mgemm<<<dim3(NN / 64, HH / 64), 256, 0, stream>>>(hhi, hlo, (u16*)(W + bw_gat) + (size_t)l * HH * HH,
                                                            nullptr, tmp, nullptr, nullptr, nullptr, HH, HH, 0);
        k_attlog<<<(NN * HEADS) / 256, 256, 0, stream>>>(tmp, W + pattS + l * HEADS * DH,
                                                         W + pattD + l * HEADS * DH, als, ald);
        k_gat_node<<<NN, 128, 0, stream>>>(esrc, rowstart, cnt, als, ald, tmp, gatb);
        // MHA branch
        k_mgemm<<<dim3(NN / 64, 384 / 64), 256, 0, stream>>>(hhi, hlo, (u16*)(W + bw_qkv) + (size_t)l * 3 * HH * HH,
                                                             W + pb_qkv + l * 3 * HH, nullptr, qkvb,
                                                             nullptr, nullptr, HH, 3 * HH, 0);
        k_mha_split<<<(NN / 32) * HEADS * KSPLIT, 128, 0, stream>>>(qkvb, pmb, plb, pob);
        k_mha_comb<<<(NN * HH) / 256, 256, 0, stream>>>(pmb, plb, pob, ahi, alo);
        k_mgemm<<<dim3(NN / 64, HH / 64), 256, 0, stream>>>(ahi, alo, (u16*)(W + bw_o) + (size_t)l * HH * HH,
                                                            W + pb_o + l * HH, big, nullptr, nullptr, nullptr,
                                                            HH, HH, 0);
        k_combine<<<(NN * HH) / 256, 256, 0, stream>>>(gatb, big, hbuf, W + pb_gat + l * HH,
                                                       W + pbn_g + l * 3 * HH, W + pbn_b + l * 3 * HH,
                                                       tmp, ohi, olo);
        k_mgemm<<<dim3(NN / 64, 256 / 64), 256, 0, stream>>>(ohi, olo, (u16*)(W + bw1) + (size_t)l * 2 * HH * HH,
                                                             W + pb1 + l * 2 * HH, nullptr, nullptr, mhi, mlo,
                                                             HH, 2 * HH, 1);
        k_mgemm<<<dim3(NN / 64, HH / 64), 256, 0, stream>>>(mhi, mlo, (u16*)(W + bw2) + (size_t)l * HH * 2 * HH,
                                                            W + pb2 + l * HH, big, nullptr, nullptr, nullptr,
                                                            2 * HH, HH, 0);
        k_final<<<(NN * HH) / 256, 256, 0, stream>>>(tmp, big, W + pbn_g + l * 3 * HH,
                                                     W + pbn_b + l * 3 * HH, hbuf, hhi, hlo);
    }
    k_out<<<NN, 64, 0, stream>>>(hbuf, W + pw_out, W + pb_out, d_out, iflag);
}

// Round 6
// 392.289 us; speedup vs baseline: 4.0881x; 1.0896x over previous
//
#include <hip/hip_runtime.h>

#define NN 4096
#define EE 262144
#define INF_ 64
#define HH 128
#define HEADS 4
#define DH 32
#define LL 2
#define NH (NN * HH)
#define KSPLIT 8

typedef unsigned short u16;
typedef unsigned int u32;
using bf16x8 = __attribute__((ext_vector_type(8))) short;
using f32x4 = __attribute__((ext_vector_type(4))) float;

__device__ __forceinline__ float bf2f(u16 v) { return __uint_as_float(((u32)v) << 16); }
__device__ __forceinline__ u16 f2bf(float f) {
    u32 u = __float_as_uint(f);
    u32 r = (u + 0x7fffu + ((u >> 16) & 1u)) >> 16;
    return (u16)r;
}

// ---------------- dtype detect ----------------
__global__ __launch_bounds__(256) void k_detect(const u16* __restrict__ x, int* __restrict__ flag) {
    __shared__ int cs[256];
    int t = threadIdx.x;
    u16 v = x[2 * t];
    int e = (v >> 7) & 0xFF;
    cs[t] = (e >= 100 && e <= 140) ? 1 : 0;
    __syncthreads();
    for (int s = 128; s > 0; s >>= 1) {
        if (t < s) cs[t] += cs[t + s];
        __syncthreads();
    }
    if (t == 0) *flag = (cs[0] >= 128) ? 1 : 0;
}

// ---------------- batched param conversion ----------------
#define MAXSEG 16
struct SegF { const void* src[MAXSEG]; int dst[MAXSEG]; int n[MAXSEG]; int cnt; };
__global__ void k_cvtf(SegF S, float* __restrict__ W, const int* __restrict__ flag) {
    int seg = blockIdx.y;
    if (seg >= S.cnt) return;
    int n = S.n[seg];
    float* d = W + S.dst[seg];
    const void* s = S.src[seg];
    int f = *flag;
    for (int i = blockIdx.x * 256 + threadIdx.x; i < n; i += gridDim.x * 256)
        d[i] = f ? bf2f(((const u16*)s)[i]) : ((const float*)s)[i];
}
struct SegB { const void* src[8]; u16* dst[8]; int n[8]; int cnt; };
__global__ void k_cvtb(SegB S, const int* __restrict__ flag) {
    int seg = blockIdx.y;
    if (seg >= S.cnt) return;
    int n = S.n[seg];
    u16* d = S.dst[seg];
    const void* s = S.src[seg];
    int f = *flag;
    for (int i = blockIdx.x * 256 + threadIdx.x; i < n; i += gridDim.x * 256)
        d[i] = f ? ((const u16*)s)[i] : f2bf(((const float*)s)[i]);
}

__global__ void k_split(const float* __restrict__ src, u16* __restrict__ hi, u16* __restrict__ lo, int n) {
    int i = blockIdx.x * blockDim.x + threadIdx.x;
    if (i >= n) return;
    float v = src[i];
    u16 h = f2bf(v);
    hi[i] = h;
    lo[i] = f2bf(v - bf2f(h));
}

// ---------------- CSR build ----------------
__global__ void k_zero(int* cnt) {
    int t = blockIdx.x * blockDim.x + threadIdx.x;
    if (t < NN) cnt[t] = 0;
}
__global__ void k_hist(const int* __restrict__ dst, int* __restrict__ cnt) {
    int e = blockIdx.x * blockDim.x + threadIdx.x;
    if (e < EE) atomicAdd(&cnt[dst[e]], 1);
}
__global__ __launch_bounds__(256) void k_scan(const int* __restrict__ cnt, int* __restrict__ rowstart,
                                              int* __restrict__ cursor) {
    __shared__ int part[256];
    int t = threadIdx.x;
    int loc[16];
    int s = 0;
#pragma unroll
    for (int i = 0; i < 16; ++i) { loc[i] = s; s += cnt[t * 16 + i]; }
    part[t] = s;
    __syncthreads();
    for (int off = 1; off < 256; off <<= 1) {
        int v = part[t];
        int a = (t >= off) ? part[t - off] : 0;
        __syncthreads();
        part[t] = v + a;
        __syncthreads();
    }
    int base = (t == 0) ? 0 : part[t - 1];
#pragma unroll
    for (int i = 0; i < 16; ++i) {
        rowstart[t * 16 + i] = base + loc[i];
        cursor[t * 16 + i] = base + loc[i];
    }
}
__global__ void k_scatter(const int* __restrict__ src, const int* __restrict__ dst,
                          int* __restrict__ cursor, int* __restrict__ esrc) {
    int e = blockIdx.x * blockDim.x + threadIdx.x;
    if (e < EE) {
        int d = dst[e];
        int p = atomicAdd(&cursor[d], 1);
        esrc[p] = src[e];
    }
}

// ---------------- MFMA GEMM: C[M,J] = (Ahi+Alo)[M,K] * W[J,K]^T + bias ----------------
__global__ __launch_bounds__(256) void k_mgemm(const u16* __restrict__ Ahi, const u16* __restrict__ Alo,
                                               const u16* __restrict__ Wb, const float* __restrict__ bias,
                                               float* __restrict__ outf, u16* __restrict__ outb16,
                                               u16* __restrict__ outhi, u16* __restrict__ outlo,
                                               int K, int J, int relu) {
    int wave = threadIdx.x >> 6, lane = threadIdx.x & 63;
    int grp = lane >> 4, lcol = lane & 15;
    int m0 = blockIdx.x * 64 + wave * 16;
    int j0 = blockIdx.y * 64;
    f32x4 acc[4];
#pragma unroll
    for (int s = 0; s < 4; ++s) acc[s] = (f32x4){0.f, 0.f, 0.f, 0.f};
    const u16* ah = Ahi + (size_t)(m0 + lcol) * K + grp * 8;
    const u16* al = Alo + (size_t)(m0 + lcol) * K + grp * 8;
    const u16* wb = Wb + (size_t)(j0 + lcol) * K + grp * 8;
    for (int k = 0; k < K; k += 32) {
        bf16x8 va = *(const bf16x8*)(ah + k);
        bf16x8 vl = *(const bf16x8*)(al + k);
#pragma unroll
        for (int s = 0; s < 4; ++s) {
            bf16x8 vw = *(const bf16x8*)(wb + (size_t)s * 16 * K + k);
            acc[s] = __builtin_amdgcn_mfma_f32_16x16x32_bf16(va, vw, acc[s], 0, 0, 0);
            acc[s] = __builtin_amdgcn_mfma_f32_16x16x32_bf16(vl, vw, acc[s], 0, 0, 0);
        }
    }
#pragma unroll
    for (int s = 0; s < 4; ++s) {
        int col = j0 + s * 16 + lcol;
        float bs = bias ? bias[col] : 0.f;
#pragma unroll
        for (int r = 0; r < 4; ++r) {
            float v = acc[s][r] + bs;
            if (relu) v = fmaxf(v, 0.f);
            size_t idx = (size_t)(m0 + grp * 4 + r) * J + col;
            if (outf) outf[idx] = v;
            if (outb16) outb16[idx] = f2bf(v);
            if (outhi) {
                u16 hv = f2bf(v);
                outhi[idx] = hv;
                outlo[idx] = f2bf(v - bf2f(hv));
            }
        }
    }
}

__global__ void k_attlog(const float* __restrict__ xp, const float* __restrict__ asrc,
                         const float* __restrict__ adst, float* __restrict__ als, float* __restrict__ ald) {
    int t = blockIdx.x * blockDim.x + threadIdx.x;
    if (t >= NN * HEADS) return;
    int n = t >> 2, hh = t & 3;
    const float* xr = xp + (size_t)n * HH + hh * DH;
    float s1 = 0.f, s2 = 0.f;
#pragma unroll
    for (int d = 0; d < DH; ++d) {
        float v = xr[d];
        s1 += v * asrc[hh * DH + d];
        s2 += v * adst[hh * DH + d];
    }
    als[t] = s1;
    ald[t] = s2;
}

// ---------------- GAT: max pass + fused exp/denom/aggregate pass ----------------
#define GCHUNK 256
__global__ __launch_bounds__(128) void k_gat_node(const int* __restrict__ esrc, const int* __restrict__ rowstart,
                                                  const int* __restrict__ cnt, const float* __restrict__ als,
                                                  const float* __restrict__ ald, const u16* __restrict__ xpb,
                                                  float* __restrict__ gatout) {
    int n = blockIdx.x, t = threadIdx.x;
    int base = rowstart[n], c = cnt[n];
    float4 adv = ((const float4*)ald)[n];
    float ad[4] = {adv.x, adv.y, adv.z, adv.w};
    __shared__ float red[512];
    __shared__ float elds[GCHUNK * 4];
    __shared__ int slds[GCHUNK];
    // phase A: row max per head
    float mx[4] = {-INFINITY, -INFINITY, -INFINITY, -INFINITY};
    for (int i = t; i < c; i += 128) {
        int s = esrc[base + i];
        float4 as = ((const float4*)als)[s];
        float lg;
        lg = as.x + ad[0]; lg = lg >= 0.f ? lg : 0.2f * lg; mx[0] = fmaxf(mx[0], lg);
        lg = as.y + ad[1]; lg = lg >= 0.f ? lg : 0.2f * lg; mx[1] = fmaxf(mx[1], lg);
        lg = as.z + ad[2]; lg = lg >= 0.f ? lg : 0.2f * lg; mx[2] = fmaxf(mx[2], lg);
        lg = as.w + ad[3]; lg = lg >= 0.f ? lg : 0.2f * lg; mx[3] = fmaxf(mx[3], lg);
    }
#pragma unroll
    for (int h = 0; h < 4; ++h) red[h * 128 + t] = mx[h];
    __syncthreads();
    for (int s2 = 64; s2 > 0; s2 >>= 1) {
        if (t < s2) {
#pragma unroll
            for (int h = 0; h < 4; ++h)
                red[h * 128 + t] = fmaxf(red[h * 128 + t], red[h * 128 + t + s2]);
        }
        __syncthreads();
    }
    float m4[4];
#pragma unroll
    for (int h = 0; h < 4; ++h) m4[h] = red[h * 128];
    // phase B+C fused, chunked
    float dsum[4] = {0.f, 0.f, 0.f, 0.f};
    float acc = 0.f;
    int ht = t >> 5;
    for (int ch = 0; ch < c; ch += GCHUNK) {
        int cn = min(GCHUNK, c - ch);
        __syncthreads();
        for (int i = t; i < cn; i += 128) {
            int s = esrc[base + ch + i];
            slds[i] = s;
            float4 as = ((const float4*)als)[s];
            float lg, e;
            lg = as.x + ad[0]; lg = lg >= 0.f ? lg : 0.2f * lg; e = __expf(lg - m4[0]); elds[i * 4 + 0] = e; dsum[0] += e;
            lg = as.y + ad[1]; lg = lg >= 0.f ? lg : 0.2f * lg; e = __expf(lg - m4[1]); elds[i * 4 + 1] = e; dsum[1] += e;
            lg = as.z + ad[2]; lg = lg >= 0.f ? lg : 0.2f * lg; e = __expf(lg - m4[2]); elds[i * 4 + 2] = e; dsum[2] += e;
            lg = as.w + ad[3]; lg = lg >= 0.f ? lg : 0.2f * lg; e = __expf(lg - m4[3]); elds[i * 4 + 3] = e; dsum[3] += e;
        }
        __syncthreads();
        int i = 0;
        for (; i + 2 <= cn; i += 2) {
            int s0 = slds[i], s1 = slds[i + 1];
            float e0 = elds[i * 4 + ht], e1 = elds[(i + 1) * 4 + ht];
            float x0 = bf2f(xpb[(size_t)s0 * HH + t]);
            float x1 = bf2f(xpb[(size_t)s1 * HH + t]);
            acc += e0 * x0 + e1 * x1;
        }
        if (i < cn) acc += elds[i * 4 + ht] * bf2f(xpb[(size_t)slds[i] * HH + t]);
    }
    __syncthreads();
#pragma unroll
    for (int h = 0; h < 4; ++h) red[h * 128 + t] = dsum[h];
    __syncthreads();
    for (int s2 = 64; s2 > 0; s2 >>= 1) {
        if (t < s2) {
#pragma unroll
            for (int h = 0; h < 4; ++h)
                red[h * 128 + t] += red[h * 128 + t + s2];
        }
        __syncthreads();
    }
    float inv = 1.f / (red[ht * 128] + 1e-16f);
    gatout[(size_t)n * HH + t] = acc * inv;
}

// ---------------- MHA flash: K-split x8, deferred l, packed kappa-permuted P ----------------
// key permutation kappa = 4*(key&15) + (key>>4); P columns and V rows use kappa order.
#define MHA_SCALE 0.17677669529663687f
__global__ __launch_bounds__(128) void k_mha_split(const u16* __restrict__ qkvb,
                                                   float* __restrict__ PM, float* __restrict__ PL,
                                                   float* __restrict__ PO) {
    int head = blockIdx.x & 3;
    int qt = (blockIdx.x >> 2) & 127;
    int ks = blockIdx.x >> 9;
    int tid = threadIdx.x;
    int wave = tid >> 6, lane = tid & 63;
    int grp = lane >> 4, lcol = lane & 15;

    __shared__ __align__(16) u16 Klds[64][40];     // [key][dim] pad 40
    __shared__ __align__(16) u32 Vlds[32][36];     // [dim][kappa-pair] packed u32, pad 36
    __shared__ __align__(16) u16 Plds[2][16][72];  // per-wave [qrow][kappa] pad 72

    int qrow0 = qt * 32 + wave * 16;
    bf16x8 aQ = *(const bf16x8*)(qkvb + (size_t)(qrow0 + lcol) * 384 + head * 32 + grp * 8);

    f32x4 oc0 = {0.f, 0.f, 0.f, 0.f}, oc1 = {0.f, 0.f, 0.f, 0.f};
    float mrow[4] = {-INFINITY, -INFINITY, -INFINITY, -INFINITY};
    float lrow[4] = {0.f, 0.f, 0.f, 0.f};  // per-lane partial, reduced at end

    int skey = tid >> 1, shalf = (tid & 1) * 16;           // K staging map
    int vj = tid & 31, dgrp = tid >> 5;                    // V staging map
    int vkey0 = 32 * (vj & 1) + (vj >> 1);                 // kappa pair (2vj, 2vj+1)
    const u16* kbase = qkvb + 128 + head * 32 + shalf;
    const u16* vbase = qkvb + 256 + head * 32 + dgrp * 8;

    int kt0 = ks * (NN / KSPLIT);
    bf16x8 rk0 = *(const bf16x8*)(kbase + (size_t)(kt0 + skey) * 384);
    bf16x8 rk1 = *(const bf16x8*)(kbase + (size_t)(kt0 + skey) * 384 + 8);
    bf16x8 rv0 = *(const bf16x8*)(vbase + (size_t)(kt0 + vkey0) * 384);
    bf16x8 rv1 = *(const bf16x8*)(vbase + (size_t)(kt0 + vkey0 + 16) * 384);

    const int NT = (NN / KSPLIT) / 64;
    for (int t = 0; t < NT; ++t) {
        *(bf16x8*)(&Klds[skey][shalf]) = rk0;
        *(bf16x8*)(&Klds[skey][shalf + 8]) = rk1;
#pragma unroll
        for (int j = 0; j < 8; ++j)
            Vlds[dgrp * 8 + j][vj] = (u32)(u16)rv0[j] | ((u32)(u16)rv1[j] << 16);
        __syncthreads();
        if (t + 1 < NT) {
            int kn = kt0 + (t + 1) * 64;
            rk0 = *(const bf16x8*)(kbase + (size_t)(kn + skey) * 384);
            rk1 = *(const bf16x8*)(kbase + (size_t)(kn + skey) * 384 + 8);
            rv0 = *(const bf16x8*)(vbase + (size_t)(kn + vkey0) * 384);
            rv1 = *(const bf16x8*)(vbase + (size_t)(kn + vkey0 + 16) * 384);
        }
        f32x4 sc[4];
        f32x4 zero = {0.f, 0.f, 0.f, 0.f};
#pragma unroll
        for (int s = 0; s < 4; ++s) {
            bf16x8 bK = *(const bf16x8*)(&Klds[s * 16 + lcol][grp * 8]);
            sc[s] = __builtin_amdgcn_mfma_f32_16x16x32_bf16(aQ, bK, zero, 0, 0, 0);
        }
#pragma unroll
        for (int r = 0; r < 4; ++r) {
            float s0 = sc[0][r] * MHA_SCALE, s1 = sc[1][r] * MHA_SCALE;
            float s2 = sc[2][r] * MHA_SCALE, s3 = sc[3][r] * MHA_SCALE;
            float mx = fmaxf(fmaxf(s0, s1), fmaxf(s2, s3));
            mx = fmaxf(mx, __shfl_xor(mx, 1));
            mx = fmaxf(mx, __shfl_xor(mx, 2));
            mx = fmaxf(mx, __shfl_xor(mx, 4));
            mx = fmaxf(mx, __shfl_xor(mx, 8));
            float mnew = fmaxf(mrow[r], mx);
            float c = __expf(mrow[r] - mnew);
            float p0 = __expf(s0 - mnew), p1 = __expf(s1 - mnew);
            float p2 = __expf(s2 - mnew), p3 = __expf(s3 - mnew);
            lrow[r] = lrow[r] * c + ((p0 + p1) + (p2 + p3));
            mrow[r] = mnew;
            int prow = grp * 4 + r;
            // kappa = 4*lcol + s: lane's 4 p-values are contiguous -> one b64 store
            u32 lo01 = (__float_as_uint(p0) >> 16) | (__float_as_uint(p1) & 0xffff0000u);
            u32 lo23 = (__float_as_uint(p2) >> 16) | (__float_as_uint(p3) & 0xffff0000u);
            *(uint2*)(&Plds[wave][prow][4 * lcol]) = make_uint2(lo01, lo23);
            oc0[r] *= c;
            oc1[r] *= c;
        }
#pragma unroll
        for (int c2 = 0; c2 < 2; ++c2) {
            bf16x8 aP = *(const bf16x8*)(&Plds[wave][lcol][c2 * 32 + grp * 8]);
            bf16x8 bV0 = *(const bf16x8*)(&Vlds[lcol][c2 * 16 + grp * 4]);
            bf16x8 bV1 = *(const bf16x8*)(&Vlds[16 + lcol][c2 * 16 + grp * 4]);
            oc0 = __builtin_amdgcn_mfma_f32_16x16x32_bf16(aP, bV0, oc0, 0, 0, 0);
            oc1 = __builtin_amdgcn_mfma_f32_16x16x32_bf16(aP, bV1, oc1, 0, 0, 0);
        }
        __syncthreads();
    }
    // reduce per-lane l across the 16 lanes of each row-group
#pragma unroll
    for (int r = 0; r < 4; ++r) {
        lrow[r] += __shfl_xor(lrow[r], 1);
        lrow[r] += __shfl_xor(lrow[r], 2);
        lrow[r] += __shfl_xor(lrow[r], 4);
        lrow[r] += __shfl_xor(lrow[r], 8);
    }
#pragma unroll
    for (int r = 0; r < 4; ++r) {
        int row = qrow0 + grp * 4 + r;
        size_t base = ((size_t)row * HEADS + head) * KSPLIT + ks;
        PO[base * 32 + lcol] = oc0[r];
        PO[base * 32 + 16 + lcol] = oc1[r];
        if (lcol == 0) {
            PM[base] = mrow[r];
            PL[base] = lrow[r];
        }
    }
}

__global__ void k_mha_comb(const float* __restrict__ PM, const float* __restrict__ PL,
                           const float* __restrict__ PO, u16* __restrict__ atthi,
                           u16* __restrict__ attlo) {
    int t = blockIdx.x * 256 + threadIdx.x;
    if (t >= NN * HH) return;
    int row = t >> 7, col = t & 127;
    int head = col >> 5, dim = col & 31;
    size_t b0 = ((size_t)row * HEADS + head) * KSPLIT;
    float m = -INFINITY;
#pragma unroll
    for (int k = 0; k < KSPLIT; ++k) m = fmaxf(m, PM[b0 + k]);
    float l = 0.f, o = 0.f;
#pragma unroll
    for (int k = 0; k < KSPLIT; ++k) {
        float w = __expf(PM[b0 + k] - m);
        l += PL[b0 + k] * w;
        o += PO[(b0 + k) * 32 + dim] * w;
    }
    float v = o / l;
    u16 h = f2bf(v);
    atthi[t] = h;
    attlo[t] = f2bf(v - bf2f(h));
}

// ---------------- elementwise combine / final ----------------
__global__ void k_combine(const float* __restrict__ gat, const float* __restrict__ proj,
                          const float* __restrict__ h, const float* __restrict__ bgat,
                          const float* __restrict__ gam, const float* __restrict__ bet,
                          float* __restrict__ outb, u16* __restrict__ ohi, u16* __restrict__ olo) {
    int t = blockIdx.x * blockDim.x + threadIdx.x;
    if (t >= NN * HH) return;
    int j = t & (HH - 1);
    float rs = rsqrtf(1.00001f);
    float g0 = gam[j] * rs, b0 = bet[j];
    float g1 = gam[HH + j] * rs, b1 = bet[HH + j];
    float hv = h[t];
    float hl = g0 * (gat[t] + bgat[j] + hv) + b0;
    float ha = g1 * (proj[t] + hv) + b1;
    float v = hl + ha;
    outb[t] = v;
    u16 hb = f2bf(v);
    ohi[t] = hb;
    olo[t] = f2bf(v - bf2f(hb));
}

__global__ void k_final(const float* __restrict__ outb, const float* __restrict__ mlpo,
                        const float* __restrict__ gam, const float* __restrict__ bet,
                        float* __restrict__ h, u16* __restrict__ hhi, u16* __restrict__ hlo) {
    int t = blockIdx.x * blockDim.x + threadIdx.x;
    if (t >= NN * HH) return;
    int j = t & (HH - 1);
    float rs = rsqrtf(1.00001f);
    float g2 = gam[2 * HH + j] * rs, b2 = bet[2 * HH + j];
    float o2 = g2 * (outb[t] + mlpo[t]) + b2;
    float v = fmaxf(o2 + h[t], 0.f);
    h[t] = v;
    u16 hb = f2bf(v);
    hhi[t] = hb;
    hlo[t] = f2bf(v - bf2f(hb));
}

// ---------------- output projection ----------------
__global__ __launch_bounds__(64) void k_out(const float* __restrict__ h, const float* __restrict__ w,
                                            const float* __restrict__ b, void* __restrict__ yout,
                                            const int* __restrict__ flag) {
    int n = blockIdx.x, l = threadIdx.x;
    float a0 = 0.f, a1 = 0.f;
    for (int k = l; k < HH; k += 64) {
        float hv = h[(size_t)n * HH + k];
        a0 += hv * w[k];
        a1 += hv * w[HH + k];
    }
#pragma unroll
    for (int off = 32; off > 0; off >>= 1) {
        a0 += __shfl_xor(a0, off);
        a1 += __shfl_xor(a1, off);
    }
    if (l == 0) {
        float o0 = a0 + b[0], o1 = a1 + b[1];
        if (*flag) {
            u16* y = (u16*)yout;
            y[n * 2 + 0] = f2bf(o0);
            y[n * 2 + 1] = f2bf(o1);
        } else {
            float* y = (float*)yout;
            y[n * 2 + 0] = o0;
            y[n * 2 + 1] = o1;
        }
    }
}

extern "C" void kernel_launch(void* const* d_in, const int* in_sizes, int n_in,
                              void* d_out, int out_size, void* d_ws, size_t ws_size,
                              hipStream_t stream) {
    float* W = (float*)d_ws;
    size_t o = 0;
    auto take = [&](size_t n) { size_t r = o; o += n; return r; };
    size_t px    = take(NN * INF_);
    size_t pb_in = take(HH);
    size_t pattS = take(LL * HEADS * DH);
    size_t pattD = take(LL * HEADS * DH);
    size_t pb_gat = take(LL * HH);
    size_t pb_qkv = take(LL * 3 * HH);
    size_t pb_o  = take(LL * HH);
    size_t pbn_g = take(LL * 3 * HH);
    size_t pbn_b = take(LL * 3 * HH);
    size_t pb1   = take(LL * 2 * HH);
    size_t pb2   = take(LL * HH);
    size_t pw_out = take(2 * HH);
    size_t pb_out = take(2);
    auto takeb = [&](size_t nu16) { size_t r = o; o += (nu16 + 1) / 2; return r; };
    size_t bw_in  = takeb(HH * INF_);
    size_t bw_gat = takeb(LL * HH * HH);
    size_t bw_qkv = takeb(LL * 3 * HH * HH);
    size_t bw_o   = takeb(LL * HH * HH);
    size_t bw1    = takeb(LL * 2 * HH * HH);
    size_t bw2    = takeb(LL * HH * 2 * HH);
    o = (o + 127) & ~(size_t)127;
    size_t ohbuf = take(NH);
    size_t ogat  = take(NH);
    size_t obig  = take(2 * NH);
    size_t otmp  = take(NH);
    size_t oals  = take(NN * HEADS);
    size_t oald  = take(NN * HEADS);
    size_t opm   = take(NN * HEADS * KSPLIT);
    size_t opl   = take(NN * HEADS * KSPLIT);
    size_t opo   = take((size_t)NN * HEADS * KSPLIT * 32);
    size_t oqkvb = takeb(NN * 384);
    size_t oxpb  = takeb(NH);
    size_t oxhi  = takeb(NN * INF_);
    size_t oxlo  = takeb(NN * INF_);
    size_t ohhi  = takeb(NH);
    size_t ohlo  = takeb(NH);
    size_t oahi  = takeb(NH);
    size_t oalo  = takeb(NH);
    size_t oohi  = takeb(NH);
    size_t oolo  = takeb(NH);
    size_t omhi  = takeb(NN * 2 * HH);
    size_t omlo  = takeb(NN * 2 * HH);
    int* ibase    = (int*)(W + o);
    int* iflag    = ibase;
    int* cnt      = ibase + 64;
    int* rowstart = cnt + NN;
    int* cursor   = rowstart + NN;
    int* esrc     = cursor + NN;

    float* hbuf = W + ohbuf;
    float* gatb = W + ogat;
    float* big  = W + obig;
    float* tmp  = W + otmp;
    float* als  = W + oals;
    float* ald  = W + oald;
    float* pmb  = W + opm;
    float* plb  = W + opl;
    float* pob  = W + opo;
    u16* qkvb = (u16*)(W + oqkvb);
    u16* xpb  = (u16*)(W + oxpb);
    u16* xhi = (u16*)(W + oxhi), *xlo = (u16*)(W + oxlo);
    u16* hhi = (u16*)(W + ohhi), *hlo = (u16*)(W + ohlo);
    u16* ahi = (u16*)(W + oahi), *alo = (u16*)(W + oalo);
    u16* ohi = (u16*)(W + oohi), *olo = (u16*)(W + oolo);
    u16* mhi = (u16*)(W + omhi), *mlo = (u16*)(W + omlo);

    const int* src = (const int*)d_in[1];
    const int* dst = (const int*)d_in[1] + EE;

    k_detect<<<1, 256, 0, stream>>>((const u16*)d_in[0], iflag);

    SegF SF = {};
    int nf = 0;
    auto addf = [&](int idx, size_t off, int n) { SF.src[nf] = d_in[idx]; SF.dst[nf] = (int)off; SF.n[nf] = n; ++nf; };
    addf(0, px, NN * INF_);
    addf(3, pb_in, HH);
    addf(5, pattS, LL * HEADS * DH);
    addf(6, pattD, LL * HEADS * DH);
    addf(7, pb_gat, LL * HH);
    addf(9, pb_qkv, LL * 3 * HH);
    addf(11, pb_o, LL * HH);
    addf(12, pbn_g, LL * 3 * HH);
    addf(13, pbn_b, LL * 3 * HH);
    addf(15, pb1, LL * 2 * HH);
    addf(17, pb2, LL * HH);
    addf(18, pw_out, 2 * HH);
    addf(19, pb_out, 2);
    SF.cnt = nf;
    k_cvtf<<<dim3(128, nf), 256, 0, stream>>>(SF, W, iflag);

    SegB SB = {};
    int nb = 0;
    auto addb = [&](int idx, size_t off, int n) { SB.src[nb] = d_in[idx]; SB.dst[nb] = (u16*)(W + off); SB.n[nb] = n; ++nb; };
    addb(2, bw_in, HH * INF_);
    addb(4, bw_gat, LL * HH * HH);
    addb(8, bw_qkv, LL * 3 * HH * HH);
    addb(10, bw_o, LL * HH * HH);
    addb(14, bw1, LL * 2 * HH * HH);
    addb(16, bw2, LL * HH * 2 * HH);
    SB.cnt = nb;
    k_cvtb<<<dim3(128, nb), 256, 0, stream>>>(SB, iflag);

    k_split<<<(NN * INF_) / 256, 256, 0, stream>>>(W + px, xhi, xlo, NN * INF_);

    k_zero<<<16, 256, 0, stream>>>(cnt);
    k_hist<<<EE / 256, 256, 0, stream>>>(dst, cnt);
    k_scan<<<1, 256, 0, stream>>>(cnt, rowstart, cursor);
    k_scatter<<<EE / 256, 256, 0, stream>>>(src, dst, cursor, esrc);

    k_mgemm<<<dim3(NN / 64, HH / 64), 256, 0, stream>>>(xhi, xlo, (u16*)(W + bw_in), W + pb_in,
                                                        hbuf, nullptr, hhi, hlo, INF_, HH, 1);

    for (int l = 0; l < LL; ++l) {
        // GAT branch: xp -> tmp (f32) + xpb (bf16)
        k_mgemm<<<dim3(NN / 64, HH / 64), 256, 0, stream>>>(hhi, hlo, (u16*)(W + bw_gat) + (size_t)l * HH * HH,
                                                            nullptr, tmp, xpb, nullptr, nullptr, HH, HH, 0);
        k_attlog<<<(NN * HEADS) / 256, 256, 0, stream>>>(tmp, W + pattS + l * HEADS * DH,
                                                         W + pattD + l * HEADS * DH, als, ald);
        k_gat_node<<<NN, 128, 0, stream>>>(esrc, rowstart, cnt, als, ald, xpb, gatb);
        // MHA branch
        k_mgemm<<<dim3(NN / 64, 384 / 64), 256, 0, stream>>>(hhi, hlo, (u16*)(W + bw_qkv) + (size_t)l * 3 * HH * HH,
                                                             W + pb_qkv + l * 3 * HH, nullptr, qkvb,
                                                             nullptr, nullptr, HH, 3 * HH, 0);
        k_mha_split<<<(NN / 32) * HEADS * KSPLIT, 128, 0, stream>>>(qkvb, pmb, plb, pob);
        k_mha_comb<<<(NN * HH) / 256, 256, 0, stream>>>(pmb, plb, pob, ahi, alo);
        k_mgemm<<<dim3(NN / 64, HH / 64), 256, 0, stream>>>(ahi, alo, (u16*)(W + bw_o) + (size_t)l * HH * HH,
                                                            W + pb_o + l * HH, big, nullptr, nullptr, nullptr,
                                                            HH, HH, 0);
        k_combine<<<(NN * HH) / 256, 256, 0, stream>>>(gatb, big, hbuf, W + pb_gat + l * HH,
                                                       W + pbn_g + l * 3 * HH, W + pbn_b + l * 3 * HH,
                                                       tmp, ohi, olo);
        k_mgemm<<<dim3(NN / 64, 256 / 64), 256, 0, stream>>>(ohi, olo, (u16*)(W + bw1) + (size_t)l * 2 * HH * HH,
                                                             W + pb1 + l * 2 * HH, nullptr, nullptr, mhi, mlo,
                                                             HH, 2 * HH, 1);
        k_mgemm<<<dim3(NN / 64, HH / 64), 256, 0, stream>>>(mhi, mlo, (u16*)(W + bw2) + (size_t)l * HH * 2 * HH,
                                                            W + pb2 + l * HH, big, nullptr, nullptr, nullptr,
                                                            2 * HH, HH, 0);
        k_final<<<(NN * HH) / 256, 256, 0, stream>>>(tmp, big, W + pbn_g + l * 3 * HH,
                                                     W + pbn_b + l * 3 * HH, hbuf, hhi, hlo);
    }
    k_out<<<NN, 64, 0, stream>>>(hbuf, W + pw_out, W + pb_out, d_out, iflag);
}

// Round 7
// 334.961 us; speedup vs baseline: 4.7878x; 1.1711x over previous
//
#include <hip/hip_runtime.h>

#define NN 4096
#define EE 262144
#define INF_ 64
#define HH 128
#define HEADS 4
#define DH 32
#define LL 2
#define NH (NN * HH)
#define KSPLIT 8
#define L2E 1.4426950408889634f

typedef unsigned short u16;
typedef unsigned int u32;
using bf16x8 = __attribute__((ext_vector_type(8))) short;
using f32x4 = __attribute__((ext_vector_type(4))) float;

__device__ __forceinline__ float bf2f(u16 v) { return __uint_as_float(((u32)v) << 16); }
__device__ __forceinline__ u16 f2bf(float f) {
    u32 u = __float_as_uint(f);
    u32 r = (u + 0x7fffu + ((u >> 16) & 1u)) >> 16;
    return (u16)r;
}
__device__ __forceinline__ u32 encf(float f) {
    u32 b = __float_as_uint(f);
    return (b & 0x80000000u) ? ~b : (b | 0x80000000u);
}
__device__ __forceinline__ float decf(u32 u) {
    u32 b = (u & 0x80000000u) ? (u & 0x7fffffffu) : ~u;
    return __uint_as_float(b);
}

// ---------------- dtype detect ----------------
__global__ __launch_bounds__(256) void k_detect(const u16* __restrict__ x, int* __restrict__ flag) {
    __shared__ int cs[256];
    int t = threadIdx.x;
    u16 v = x[2 * t];
    int e = (v >> 7) & 0xFF;
    cs[t] = (e >= 100 && e <= 140) ? 1 : 0;
    __syncthreads();
    for (int s = 128; s > 0; s >>= 1) {
        if (t < s) cs[t] += cs[t + s];
        __syncthreads();
    }
    if (t == 0) *flag = (cs[0] >= 128) ? 1 : 0;
}

// ---------------- batched param conversion ----------------
#define MAXSEG 16
struct SegF { const void* src[MAXSEG]; int dst[MAXSEG]; int n[MAXSEG]; int cnt; };
__global__ void k_cvtf(SegF S, float* __restrict__ W, const int* __restrict__ flag) {
    int seg = blockIdx.y;
    if (seg >= S.cnt) return;
    int n = S.n[seg];
    float* d = W + S.dst[seg];
    const void* s = S.src[seg];
    int f = *flag;
    for (int i = blockIdx.x * 256 + threadIdx.x; i < n; i += gridDim.x * 256)
        d[i] = f ? bf2f(((const u16*)s)[i]) : ((const float*)s)[i];
}
struct SegB { const void* src[8]; u16* dst[8]; int n[8]; int cnt; };
__global__ void k_cvtb(SegB S, const int* __restrict__ flag) {
    int seg = blockIdx.y;
    if (seg >= S.cnt) return;
    int n = S.n[seg];
    u16* d = S.dst[seg];
    const void* s = S.src[seg];
    int f = *flag;
    for (int i = blockIdx.x * 256 + threadIdx.x; i < n; i += gridDim.x * 256)
        d[i] = f ? ((const u16*)s)[i] : f2bf(((const float*)s)[i]);
}

// dtype-aware hi/lo split straight from input x
__global__ void k_split(const void* __restrict__ src, u16* __restrict__ hi, u16* __restrict__ lo,
                        int n, const int* __restrict__ flag) {
    int i = blockIdx.x * blockDim.x + threadIdx.x;
    if (i >= n) return;
    float v = *flag ? bf2f(((const u16*)src)[i]) : ((const float*)src)[i];
    u16 h = f2bf(v);
    hi[i] = h;
    lo[i] = f2bf(v - bf2f(h));
}

// ---------------- CSR build ----------------
__global__ void k_zero(int* cnt, u32* gmax) {
    int t = blockIdx.x * blockDim.x + threadIdx.x;
    if (t < NN) cnt[t] = 0;
    if (t < 16) gmax[t] = 0;
}
__global__ void k_hist(const int* __restrict__ dst, int* __restrict__ cnt) {
    int e = blockIdx.x * blockDim.x + threadIdx.x;
    if (e < EE) atomicAdd(&cnt[dst[e]], 1);
}
__global__ __launch_bounds__(256) void k_scan(const int* __restrict__ cnt, int* __restrict__ rowstart,
                                              int* __restrict__ cursor) {
    __shared__ int part[256];
    int t = threadIdx.x;
    int loc[16];
    int s = 0;
#pragma unroll
    for (int i = 0; i < 16; ++i) { loc[i] = s; s += cnt[t * 16 + i]; }
    part[t] = s;
    __syncthreads();
    for (int off = 1; off < 256; off <<= 1) {
        int v = part[t];
        int a = (t >= off) ? part[t - off] : 0;
        __syncthreads();
        part[t] = v + a;
        __syncthreads();
    }
    int base = (t == 0) ? 0 : part[t - 1];
#pragma unroll
    for (int i = 0; i < 16; ++i) {
        rowstart[t * 16 + i] = base + loc[i];
        cursor[t * 16 + i] = base + loc[i];
    }
}
__global__ void k_scatter(const int* __restrict__ src, const int* __restrict__ dst,
                          int* __restrict__ cursor, int* __restrict__ esrc) {
    int e = blockIdx.x * blockDim.x + threadIdx.x;
    if (e < EE) {
        int d = dst[e];
        int p = atomicAdd(&cursor[d], 1);
        esrc[p] = src[e];
    }
}

// ---------------- generic MFMA GEMM, M-tile 32 (2 waves) ----------------
__global__ __launch_bounds__(128) void k_mgemm(const u16* __restrict__ Ahi, const u16* __restrict__ Alo,
                                               const u16* __restrict__ Wb, const float* __restrict__ bias,
                                               float* __restrict__ outf, u16* __restrict__ outb16,
                                               u16* __restrict__ outhi, u16* __restrict__ outlo,
                                               int K, int J, int relu) {
    int wave = threadIdx.x >> 6, lane = threadIdx.x & 63;
    int grp = lane >> 4, lcol = lane & 15;
    int m0 = blockIdx.x * 32 + wave * 16;
    int j0 = blockIdx.y * 64;
    f32x4 acc[4];
#pragma unroll
    for (int s = 0; s < 4; ++s) acc[s] = (f32x4){0.f, 0.f, 0.f, 0.f};
    const u16* ah = Ahi + (size_t)(m0 + lcol) * K + grp * 8;
    const u16* al = Alo + (size_t)(m0 + lcol) * K + grp * 8;
    const u16* wb = Wb + (size_t)(j0 + lcol) * K + grp * 8;
    for (int k = 0; k < K; k += 32) {
        bf16x8 va = *(const bf16x8*)(ah + k);
        bf16x8 vl = *(const bf16x8*)(al + k);
#pragma unroll
        for (int s = 0; s < 4; ++s) {
            bf16x8 vw = *(const bf16x8*)(wb + (size_t)s * 16 * K + k);
            acc[s] = __builtin_amdgcn_mfma_f32_16x16x32_bf16(va, vw, acc[s], 0, 0, 0);
            acc[s] = __builtin_amdgcn_mfma_f32_16x16x32_bf16(vl, vw, acc[s], 0, 0, 0);
        }
    }
#pragma unroll
    for (int s = 0; s < 4; ++s) {
        int col = j0 + s * 16 + lcol;
        float bs = bias ? bias[col] : 0.f;
#pragma unroll
        for (int r = 0; r < 4; ++r) {
            float v = acc[s][r] + bs;
            if (relu) v = fmaxf(v, 0.f);
            size_t idx = (size_t)(m0 + grp * 4 + r) * J + col;
            if (outf) outf[idx] = v;
            if (outb16) outb16[idx] = f2bf(v);
            if (outhi) {
                u16 hv = f2bf(v);
                outhi[idx] = hv;
                outlo[idx] = f2bf(v - bf2f(hv));
            }
        }
    }
}

// ---------------- fused GAT-xp + QKV GEMM (J=512 in one launch) ----------------
__global__ __launch_bounds__(128) void k_gemm_gq(const u16* __restrict__ Ahi, const u16* __restrict__ Alo,
                                                 const u16* __restrict__ wgat, const u16* __restrict__ wqkv,
                                                 const float* __restrict__ bqkv,
                                                 float* __restrict__ xpf, u16* __restrict__ xpb,
                                                 u16* __restrict__ qkvb) {
    int wave = threadIdx.x >> 6, lane = threadIdx.x & 63;
    int grp = lane >> 4, lcol = lane & 15;
    int m0 = blockIdx.x * 32 + wave * 16;
    int jb = blockIdx.y;
    int j0 = jb * 64;
    const u16* Wb = (jb < 2) ? (wgat + (size_t)j0 * HH) : (wqkv + (size_t)(j0 - 128) * HH);
    f32x4 acc[4];
#pragma unroll
    for (int s = 0; s < 4; ++s) acc[s] = (f32x4){0.f, 0.f, 0.f, 0.f};
    const u16* ah = Ahi + (size_t)(m0 + lcol) * HH + grp * 8;
    const u16* al = Alo + (size_t)(m0 + lcol) * HH + grp * 8;
    const u16* wb = Wb + (size_t)lcol * HH + grp * 8;
    for (int k = 0; k < HH; k += 32) {
        bf16x8 va = *(const bf16x8*)(ah + k);
        bf16x8 vl = *(const bf16x8*)(al + k);
#pragma unroll
        for (int s = 0; s < 4; ++s) {
            bf16x8 vw = *(const bf16x8*)(wb + (size_t)s * 16 * HH + k);
            acc[s] = __builtin_amdgcn_mfma_f32_16x16x32_bf16(va, vw, acc[s], 0, 0, 0);
            acc[s] = __builtin_amdgcn_mfma_f32_16x16x32_bf16(vl, vw, acc[s], 0, 0, 0);
        }
    }
    if (jb < 2) {
#pragma unroll
        for (int s = 0; s < 4; ++s) {
            int col = j0 + s * 16 + lcol;
#pragma unroll
            for (int r = 0; r < 4; ++r) {
                float v = acc[s][r];
                size_t idx = (size_t)(m0 + grp * 4 + r) * HH + col;
                xpf[idx] = v;
                xpb[idx] = f2bf(v);
            }
        }
    } else {
#pragma unroll
        for (int s = 0; s < 4; ++s) {
            int colq = j0 - 128 + s * 16 + lcol;
            float bs = bqkv[colq];
#pragma unroll
            for (int r = 0; r < 4; ++r)
                qkvb[(size_t)(m0 + grp * 4 + r) * 384 + colq] = f2bf(acc[s][r] + bs);
        }
    }
}

// ---------------- w_o GEMM + combine fused epilogue ----------------
__global__ __launch_bounds__(128) void k_gemm_wo(const u16* __restrict__ Ahi, const u16* __restrict__ Alo,
                                                 const u16* __restrict__ Wb, const float* __restrict__ bias,
                                                 const float* __restrict__ gatb, const float* __restrict__ hbuf,
                                                 const float* __restrict__ bgat, const float* __restrict__ gam,
                                                 const float* __restrict__ bet,
                                                 float* __restrict__ outb, u16* __restrict__ ohi,
                                                 u16* __restrict__ olo) {
    int wave = threadIdx.x >> 6, lane = threadIdx.x & 63;
    int grp = lane >> 4, lcol = lane & 15;
    int m0 = blockIdx.x * 32 + wave * 16;
    int j0 = blockIdx.y * 64;
    f32x4 acc[4];
#pragma unroll
    for (int s = 0; s < 4; ++s) acc[s] = (f32x4){0.f, 0.f, 0.f, 0.f};
    const u16* ah = Ahi + (size_t)(m0 + lcol) * HH + grp * 8;
    const u16* al = Alo + (size_t)(m0 + lcol) * HH + grp * 8;
    const u16* wb = Wb + (size_t)(j0 + lcol) * HH + grp * 8;
    for (int k = 0; k < HH; k += 32) {
        bf16x8 va = *(const bf16x8*)(ah + k);
        bf16x8 vl = *(const bf16x8*)(al + k);
#pragma unroll
        for (int s = 0; s < 4; ++s) {
            bf16x8 vw = *(const bf16x8*)(wb + (size_t)s * 16 * HH + k);
            acc[s] = __builtin_amdgcn_mfma_f32_16x16x32_bf16(va, vw, acc[s], 0, 0, 0);
            acc[s] = __builtin_amdgcn_mfma_f32_16x16x32_bf16(vl, vw, acc[s], 0, 0, 0);
        }
    }
    float rs = rsqrtf(1.00001f);
#pragma unroll
    for (int s = 0; s < 4; ++s) {
        int col = j0 + s * 16 + lcol;
        float bs = bias[col];
        float g0 = gam[col] * rs, b0 = bet[col];
        float g1 = gam[HH + col] * rs, b1 = bet[HH + col];
        float bg = bgat[col];
#pragma unroll
        for (int r = 0; r < 4; ++r) {
            size_t idx = (size_t)(m0 + grp * 4 + r) * HH + col;
            float proj = acc[s][r] + bs;
            float hv = hbuf[idx];
            float hl = g0 * (gatb[idx] + bg + hv) + b0;
            float ha = g1 * (proj + hv) + b1;
            float v = hl + ha;
            outb[idx] = v;
            u16 hb = f2bf(v);
            ohi[idx] = hb;
            olo[idx] = f2bf(v - bf2f(hb));
        }
    }
}

// ---------------- w2 GEMM + final fused epilogue ----------------
__global__ __launch_bounds__(128) void k_gemm_w2(const u16* __restrict__ Ahi, const u16* __restrict__ Alo,
                                                 const u16* __restrict__ Wb, const float* __restrict__ bias,
                                                 const float* __restrict__ outb, const float* __restrict__ gam2,
                                                 const float* __restrict__ bet2,
                                                 float* __restrict__ hbuf, u16* __restrict__ hhi,
                                                 u16* __restrict__ hlo) {
    int wave = threadIdx.x >> 6, lane = threadIdx.x & 63;
    int grp = lane >> 4, lcol = lane & 15;
    int m0 = blockIdx.x * 32 + wave * 16;
    int j0 = blockIdx.y * 64;
    const int K = 2 * HH;
    f32x4 acc[4];
#pragma unroll
    for (int s = 0; s < 4; ++s) acc[s] = (f32x4){0.f, 0.f, 0.f, 0.f};
    const u16* ah = Ahi + (size_t)(m0 + lcol) * K + grp * 8;
    const u16* al = Alo + (size_t)(m0 + lcol) * K + grp * 8;
    const u16* wb = Wb + (size_t)(j0 + lcol) * K + grp * 8;
    for (int k = 0; k < K; k += 32) {
        bf16x8 va = *(const bf16x8*)(ah + k);
        bf16x8 vl = *(const bf16x8*)(al + k);
#pragma unroll
        for (int s = 0; s < 4; ++s) {
            bf16x8 vw = *(const bf16x8*)(wb + (size_t)s * 16 * K + k);
            acc[s] = __builtin_amdgcn_mfma_f32_16x16x32_bf16(va, vw, acc[s], 0, 0, 0);
            acc[s] = __builtin_amdgcn_mfma_f32_16x16x32_bf16(vl, vw, acc[s], 0, 0, 0);
        }
    }
    float rs = rsqrtf(1.00001f);
#pragma unroll
    for (int s = 0; s < 4; ++s) {
        int col = j0 + s * 16 + lcol;
        float bs = bias[col];
        float g2 = gam2[col] * rs, b2 = bet2[col];
#pragma unroll
        for (int r = 0; r < 4; ++r) {
            size_t idx = (size_t)(m0 + grp * 4 + r) * HH + col;
            float mlpo = acc[s][r] + bs;
            float o2 = g2 * (outb[idx] + mlpo) + b2;
            float v = fmaxf(o2 + hbuf[idx], 0.f);
            hbuf[idx] = v;
            u16 hb = f2bf(v);
            hhi[idx] = hb;
            hlo[idx] = f2bf(v - bf2f(hb));
        }
    }
}

// ---------------- attlog + per-head global-max atomics ----------------
__global__ __launch_bounds__(256) void k_attlog(const float* __restrict__ xp, const float* __restrict__ asrc,
                                                const float* __restrict__ adst, float* __restrict__ als,
                                                float* __restrict__ ald, u32* __restrict__ gmax) {
    int t = blockIdx.x * 256 + threadIdx.x;
    int n = t >> 2, hh = t & 3;
    const float* xr = xp + (size_t)n * HH + hh * DH;
    float s1 = 0.f, s2 = 0.f;
#pragma unroll
    for (int d = 0; d < DH; ++d) {
        float v = xr[d];
        s1 += v * asrc[hh * DH + d];
        s2 += v * adst[hh * DH + d];
    }
    als[t] = s1;
    ald[t] = s2;
    __shared__ float red[256];
    int lt = threadIdx.x;
    red[lt] = s1;
    __syncthreads();
    for (int off = 128; off >= 4; off >>= 1) {
        if (lt < off) red[lt] = fmaxf(red[lt], red[lt + off]);
        __syncthreads();
    }
    if (lt < 4) atomicMax(&gmax[lt], encf(red[lt]));
    __syncthreads();
    red[lt] = s2;
    __syncthreads();
    for (int off = 128; off >= 4; off >>= 1) {
        if (lt < off) red[lt] = fmaxf(red[lt], red[lt + off]);
        __syncthreads();
    }
    if (lt < 4) atomicMax(&gmax[4 + lt], encf(red[lt]));
}

// ---------------- GAT: single fused pass with global-max bound ----------------
#define GCHUNK 256
__global__ __launch_bounds__(128) void k_gat_node(const int* __restrict__ esrc, const int* __restrict__ rowstart,
                                                  const int* __restrict__ cnt, const float* __restrict__ als,
                                                  const float* __restrict__ ald, const u16* __restrict__ xpb,
                                                  float* __restrict__ gatout, const u32* __restrict__ gmax) {
    int n = blockIdx.x, t = threadIdx.x;
    int base = rowstart[n], c = cnt[n];
    float4 adv = ((const float4*)ald)[n];
    float ad[4] = {adv.x, adv.y, adv.z, adv.w};
    float M2[4];
#pragma unroll
    for (int h = 0; h < 4; ++h) {
        float bound = decf(gmax[h]) + decf(gmax[4 + h]);
        float M = bound >= 0.f ? bound : 0.2f * bound;
        M2[h] = M * L2E;
    }
    __shared__ float red[512];
    __shared__ float elds[GCHUNK * 4];
    __shared__ int slds[GCHUNK];
    float dsum[4] = {0.f, 0.f, 0.f, 0.f};
    float acc = 0.f;
    int ht = t >> 5;
    for (int ch = 0; ch < c; ch += GCHUNK) {
        int cn = min(GCHUNK, c - ch);
        __syncthreads();
        for (int i = t; i < cn; i += 128) {
            int s = esrc[base + ch + i];
            slds[i] = s;
            float4 as = ((const float4*)als)[s];
            float lg, e;
            lg = as.x + ad[0]; lg = lg >= 0.f ? lg : 0.2f * lg; e = __builtin_exp2f(lg * L2E - M2[0]); elds[i * 4 + 0] = e; dsum[0] += e;
            lg = as.y + ad[1]; lg = lg >= 0.f ? lg : 0.2f * lg; e = __builtin_exp2f(lg * L2E - M2[1]); elds[i * 4 + 1] = e; dsum[1] += e;
            lg = as.z + ad[2]; lg = lg >= 0.f ? lg : 0.2f * lg; e = __builtin_exp2f(lg * L2E - M2[2]); elds[i * 4 + 2] = e; dsum[2] += e;
            lg = as.w + ad[3]; lg = lg >= 0.f ? lg : 0.2f * lg; e = __builtin_exp2f(lg * L2E - M2[3]); elds[i * 4 + 3] = e; dsum[3] += e;
        }
        __syncthreads();
        int i = 0;
        for (; i + 2 <= cn; i += 2) {
            int s0 = slds[i], s1 = slds[i + 1];
            float e0 = elds[i * 4 + ht], e1 = elds[(i + 1) * 4 + ht];
            float x0 = bf2f(xpb[(size_t)s0 * HH + t]);
            float x1 = bf2f(xpb[(size_t)s1 * HH + t]);
            acc += e0 * x0 + e1 * x1;
        }
        if (i < cn) acc += elds[i * 4 + ht] * bf2f(xpb[(size_t)slds[i] * HH + t]);
    }
    __syncthreads();
#pragma unroll
    for (int h = 0; h < 4; ++h) red[h * 128 + t] = dsum[h];
    __syncthreads();
    for (int s2 = 64; s2 > 0; s2 >>= 1) {
        if (t < s2) {
#pragma unroll
            for (int h = 0; h < 4; ++h)
                red[h * 128 + t] += red[h * 128 + t + s2];
        }
        __syncthreads();
    }
    float inv = 1.f / (red[ht * 128] + 1e-16f);
    gatout[(size_t)n * HH + t] = acc * inv;
}

// ---------------- MHA flash v3: 4-wave blocks, shared 4-row max, exp2 domain ----------------
__global__ __launch_bounds__(256) void k_mha_split(const u16* __restrict__ qkvb,
                                                   float* __restrict__ PM, float* __restrict__ PL,
                                                   float* __restrict__ PO) {
    const float C1 = 0.17677669529663687f * L2E;  // scale * log2(e)
    int head = blockIdx.x & 3;
    int qt = (blockIdx.x >> 2) & 63;
    int ks = blockIdx.x >> 8;
    int tid = threadIdx.x;
    int wave = tid >> 6, lane = tid & 63;
    int grp = lane >> 4, lcol = lane & 15;

    __shared__ __align__(16) u16 Klds[64][40];     // [key][dim] pad 40
    __shared__ __align__(16) u32 Vlds[32][36];     // [dim][kappa-pair] packed u32
    __shared__ __align__(16) u16 Plds[4][16][66];  // per-wave [qrow][kappa] pad 66

    int qrow0 = qt * 64 + wave * 16;
    bf16x8 aQ = *(const bf16x8*)(qkvb + (size_t)(qrow0 + lcol) * 384 + head * 32 + grp * 8);

    f32x4 oc0 = {0.f, 0.f, 0.f, 0.f}, oc1 = {0.f, 0.f, 0.f, 0.f};
    float msh = -INFINITY;                 // shared max for this wave's 4-row group (log2 units)
    float lrow[4] = {0.f, 0.f, 0.f, 0.f};  // per-lane partials

    // staging maps: waves 0-1 stage K, waves 2-3 stage V
    int isK = (tid < 128);
    int st = tid & 127;
    int skey = st >> 1, shalf = (st & 1) * 16;
    int vj = st & 31, dgrp = st >> 5;               // dgrp 0..3
    int vkey0 = 32 * (vj & 1) + (vj >> 1);          // kappa pair (2vj', 2vj'+1)
    const u16* kptr = qkvb + 128 + head * 32 + shalf;
    const u16* vptr = qkvb + 256 + head * 32 + dgrp * 8;

    int kt0 = ks * (NN / KSPLIT);
    bf16x8 r0, r1;
    if (isK) {
        r0 = *(const bf16x8*)(kptr + (size_t)(kt0 + skey) * 384);
        r1 = *(const bf16x8*)(kptr + (size_t)(kt0 + skey) * 384 + 8);
    } else {
        r0 = *(const bf16x8*)(vptr + (size_t)(kt0 + vkey0) * 384);
        r1 = *(const bf16x8*)(vptr + (size_t)(kt0 + vkey0 + 16) * 384);
    }

    const int NT = (NN / KSPLIT) / 64;
    for (int t = 0; t < NT; ++t) {
        if (isK) {
            *(bf16x8*)(&Klds[skey][shalf]) = r0;
            *(bf16x8*)(&Klds[skey][shalf + 8]) = r1;
        } else {
#pragma unroll
            for (int j = 0; j < 8; ++j)
                Vlds[dgrp * 8 + j][vj] = (u32)(u16)r0[j] | ((u32)(u16)r1[j] << 16);
        }
        __syncthreads();
        if (t + 1 < NT) {
            int kn = kt0 + (t + 1) * 64;
            if (isK) {
                r0 = *(const bf16x8*)(kptr + (size_t)(kn + skey) * 384);
                r1 = *(const bf16x8*)(kptr + (size_t)(kn + skey) * 384 + 8);
            } else {
                r0 = *(const bf16x8*)(vptr + (size_t)(kn + vkey0) * 384);
                r1 = *(const bf16x8*)(vptr + (size_t)(kn + vkey0 + 16) * 384);
            }
        }
        f32x4 sc[4];
        f32x4 zero = {0.f, 0.f, 0.f, 0.f};
#pragma unroll
        for (int s = 0; s < 4; ++s) {
            bf16x8 bK = *(const bf16x8*)(&Klds[s * 16 + lcol][grp * 8]);
            sc[s] = __builtin_amdgcn_mfma_f32_16x16x32_bf16(aQ, bK, zero, 0, 0, 0);
        }
        float tv[4][4];
        float mymax = -INFINITY;
#pragma unroll
        for (int s = 0; s < 4; ++s)
#pragma unroll
            for (int r = 0; r < 4; ++r) {
                float x = sc[s][r] * C1;
                tv[s][r] = x;
                mymax = fmaxf(mymax, x);
            }
        mymax = fmaxf(mymax, __shfl_xor(mymax, 1));
        mymax = fmaxf(mymax, __shfl_xor(mymax, 2));
        mymax = fmaxf(mymax, __shfl_xor(mymax, 4));
        mymax = fmaxf(mymax, __shfl_xor(mymax, 8));
        float mnew = fmaxf(msh, mymax);
        float cc = __builtin_exp2f(msh - mnew);
        msh = mnew;
#pragma unroll
        for (int r = 0; r < 4; ++r) {
            float p0 = __builtin_exp2f(tv[0][r] - mnew);
            float p1 = __builtin_exp2f(tv[1][r] - mnew);
            float p2 = __builtin_exp2f(tv[2][r] - mnew);
            float p3 = __builtin_exp2f(tv[3][r] - mnew);
            lrow[r] = lrow[r] * cc + ((p0 + p1) + (p2 + p3));
            u32 lo01 = (__float_as_uint(p0) >> 16) | (__float_as_uint(p1) & 0xffff0000u);
            u32 lo23 = (__float_as_uint(p2) >> 16) | (__float_as_uint(p3) & 0xffff0000u);
            *(uint2*)(&Plds[wave][grp * 4 + r][4 * lcol]) = make_uint2(lo01, lo23);
        }
        oc0 *= cc;
        oc1 *= cc;
#pragma unroll
        for (int c2 = 0; c2 < 2; ++c2) {
            bf16x8 aP = *(const bf16x8*)(&Plds[wave][lcol][c2 * 32 + grp * 8]);
            bf16x8 bV0 = *(const bf16x8*)(&Vlds[lcol][c2 * 16 + grp * 4]);
            bf16x8 bV1 = *(const bf16x8*)(&Vlds[16 + lcol][c2 * 16 + grp * 4]);
            oc0 = __builtin_amdgcn_mfma_f32_16x16x32_bf16(aP, bV0, oc0, 0, 0, 0);
            oc1 = __builtin_amdgcn_mfma_f32_16x16x32_bf16(aP, bV1, oc1, 0, 0, 0);
        }
        __syncthreads();
    }
#pragma unroll
    for (int r = 0; r < 4; ++r) {
        lrow[r] += __shfl_xor(lrow[r], 1);
        lrow[r] += __shfl_xor(lrow[r], 2);
        lrow[r] += __shfl_xor(lrow[r], 4);
        lrow[r] += __shfl_xor(lrow[r], 8);
    }
#pragma unroll
    for (int r = 0; r < 4; ++r) {
        int row = qrow0 + grp * 4 + r;
        size_t base = ((size_t)row * HEADS + head) * KSPLIT + ks;
        PO[base * 32 + lcol] = oc0[r];
        PO[base * 32 + 16 + lcol] = oc1[r];
        if (lcol == 0) {
            PM[base] = msh;
            PL[base] = lrow[r];
        }
    }
}

__global__ void k_mha_comb(const float* __restrict__ PM, const float* __restrict__ PL,
                           const float* __restrict__ PO, u16* __restrict__ atthi,
                           u16* __restrict__ attlo) {
    int t = blockIdx.x * 256 + threadIdx.x;
    if (t >= NN * HH) return;
    int row = t >> 7, col = t & 127;
    int head = col >> 5, dim = col & 31;
    size_t b0 = ((size_t)row * HEADS + head) * KSPLIT;
    float m = -INFINITY;
#pragma unroll
    for (int k = 0; k < KSPLIT; ++k) m = fmaxf(m, PM[b0 + k]);
    float l = 0.f, o = 0.f;
#pragma unroll
    for (int k = 0; k < KSPLIT; ++k) {
        float w = __builtin_exp2f(PM[b0 + k] - m);
        l += PL[b0 + k] * w;
        o += PO[(b0 + k) * 32 + dim] * w;
    }
    float v = o / l;
    u16 h = f2bf(v);
    atthi[t] = h;
    attlo[t] = f2bf(v - bf2f(h));
}

// ---------------- output projection ----------------
__global__ __launch_bounds__(64) void k_out(const float* __restrict__ h, const float* __restrict__ w,
                                            const float* __restrict__ b, void* __restrict__ yout,
                                            const int* __restrict__ flag) {
    int n = blockIdx.x, l = threadIdx.x;
    float a0 = 0.f, a1 = 0.f;
    for (int k = l; k < HH; k += 64) {
        float hv = h[(size_t)n * HH + k];
        a0 += hv * w[k];
        a1 += hv * w[HH + k];
    }
#pragma unroll
    for (int off = 32; off > 0; off >>= 1) {
        a0 += __shfl_xor(a0, off);
        a1 += __shfl_xor(a1, off);
    }
    if (l == 0) {
        float o0 = a0 + b[0], o1 = a1 + b[1];
        if (*flag) {
            u16* y = (u16*)yout;
            y[n * 2 + 0] = f2bf(o0);
            y[n * 2 + 1] = f2bf(o1);
        } else {
            float* y = (float*)yout;
            y[n * 2 + 0] = o0;
            y[n * 2 + 1] = o1;
        }
    }
}

extern "C" void kernel_launch(void* const* d_in, const int* in_sizes, int n_in,
                              void* d_out, int out_size, void* d_ws, size_t ws_size,
                              hipStream_t stream) {
    float* W = (float*)d_ws;
    size_t o = 0;
    auto take = [&](size_t n) { size_t r = o; o += n; return r; };
    size_t pb_in = take(HH);
    size_t pattS = take(LL * HEADS * DH);
    size_t pattD = take(LL * HEADS * DH);
    size_t pb_gat = take(LL * HH);
    size_t pb_qkv = take(LL * 3 * HH);
    size_t pb_o  = take(LL * HH);
    size_t pbn_g = take(LL * 3 * HH);
    size_t pbn_b = take(LL * 3 * HH);
    size_t pb1   = take(LL * 2 * HH);
    size_t pb2   = take(LL * HH);
    size_t pw_out = take(2 * HH);
    size_t pb_out = take(2);
    auto takeb = [&](size_t nu16) { size_t r = o; o += (nu16 + 1) / 2; return r; };
    size_t bw_in  = takeb(HH * INF_);
    size_t bw_gat = takeb(LL * HH * HH);
    size_t bw_qkv = takeb(LL * 3 * HH * HH);
    size_t bw_o   = takeb(LL * HH * HH);
    size_t bw1    = takeb(LL * 2 * HH * HH);
    size_t bw2    = takeb(LL * HH * 2 * HH);
    o = (o + 127) & ~(size_t)127;
    size_t ohbuf = take(NH);
    size_t ogat  = take(NH);
    size_t otmp  = take(NH);
    size_t oals  = take(NN * HEADS);
    size_t oald  = take(NN * HEADS);
    size_t opm   = take(NN * HEADS * KSPLIT);
    size_t opl   = take(NN * HEADS * KSPLIT);
    size_t opo   = take((size_t)NN * HEADS * KSPLIT * 32);
    size_t oqkvb = takeb(NN * 384);
    size_t oxpb  = takeb(NH);
    size_t oxhi  = takeb(NN * INF_);
    size_t oxlo  = takeb(NN * INF_);
    size_t ohhi  = takeb(NH);
    size_t ohlo  = takeb(NH);
    size_t oahi  = takeb(NH);
    size_t oalo  = takeb(NH);
    size_t oohi  = takeb(NH);
    size_t oolo  = takeb(NH);
    size_t omhi  = takeb(NN * 2 * HH);
    size_t omlo  = takeb(NN * 2 * HH);
    int* ibase    = (int*)(W + o);
    int* iflag    = ibase;
    int* cnt      = ibase + 64;
    int* rowstart = cnt + NN;
    int* cursor   = rowstart + NN;
    int* esrc     = cursor + NN;
    u32* gmax     = (u32*)(esrc + EE);   // 16 slots: 8 per layer

    float* hbuf = W + ohbuf;
    float* gatb = W + ogat;
    float* tmp  = W + otmp;
    float* als  = W + oals;
    float* ald  = W + oald;
    float* pmb  = W + opm;
    float* plb  = W + opl;
    float* pob  = W + opo;
    u16* qkvb = (u16*)(W + oqkvb);
    u16* xpb  = (u16*)(W + oxpb);
    u16* xhi = (u16*)(W + oxhi), *xlo = (u16*)(W + oxlo);
    u16* hhi = (u16*)(W + ohhi), *hlo = (u16*)(W + ohlo);
    u16* ahi = (u16*)(W + oahi), *alo = (u16*)(W + oalo);
    u16* ohi = (u16*)(W + oohi), *olo = (u16*)(W + oolo);
    u16* mhi = (u16*)(W + omhi), *mlo = (u16*)(W + omlo);

    const int* src = (const int*)d_in[1];
    const int* dst = (const int*)d_in[1] + EE;

    k_detect<<<1, 256, 0, stream>>>((const u16*)d_in[0], iflag);

    SegF SF = {};
    int nf = 0;
    auto addf = [&](int idx, size_t off, int n) { SF.src[nf] = d_in[idx]; SF.dst[nf] = (int)off; SF.n[nf] = n; ++nf; };
    addf(3, pb_in, HH);
    addf(5, pattS, LL * HEADS * DH);
    addf(6, pattD, LL * HEADS * DH);
    addf(7, pb_gat, LL * HH);
    addf(9, pb_qkv, LL * 3 * HH);
    addf(11, pb_o, LL * HH);
    addf(12, pbn_g, LL * 3 * HH);
    addf(13, pbn_b, LL * 3 * HH);
    addf(15, pb1, LL * 2 * HH);
    addf(17, pb2, LL * HH);
    addf(18, pw_out, 2 * HH);
    addf(19, pb_out, 2);
    SF.cnt = nf;
    k_cvtf<<<dim3(8, nf), 256, 0, stream>>>(SF, W, iflag);

    SegB SB = {};
    int nb = 0;
    auto addb = [&](int idx, size_t off, int n) { SB.src[nb] = d_in[idx]; SB.dst[nb] = (u16*)(W + off); SB.n[nb] = n; ++nb; };
    addb(2, bw_in, HH * INF_);
    addb(4, bw_gat, LL * HH * HH);
    addb(8, bw_qkv, LL * 3 * HH * HH);
    addb(10, bw_o, LL * HH * HH);
    addb(14, bw1, LL * 2 * HH * HH);
    addb(16, bw2, LL * HH * 2 * HH);
    SB.cnt = nb;
    k_cvtb<<<dim3(128, nb), 256, 0, stream>>>(SB, iflag);

    k_split<<<(NN * INF_) / 256, 256, 0, stream>>>(d_in[0], xhi, xlo, NN * INF_, iflag);

    k_zero<<<16, 256, 0, stream>>>(cnt, gmax);
    k_hist<<<EE / 256, 256, 0, stream>>>(dst, cnt);
    k_scan<<<1, 256, 0, stream>>>(cnt, rowstart, cursor);
    k_scatter<<<EE / 256, 256, 0, stream>>>(src, dst, cursor, esrc);

    k_mgemm<<<dim3(NN / 32, HH / 64), 128, 0, stream>>>(xhi, xlo, (u16*)(W + bw_in), W + pb_in,
                                                        hbuf, nullptr, hhi, hlo, INF_, HH, 1);

    for (int l = 0; l < LL; ++l) {
        // fused GAT-xp + QKV projection
        k_gemm_gq<<<dim3(NN / 32, 8), 128, 0, stream>>>(hhi, hlo,
                                                        (u16*)(W + bw_gat) + (size_t)l * HH * HH,
                                                        (u16*)(W + bw_qkv) + (size_t)l * 3 * HH * HH,
                                                        W + pb_qkv + l * 3 * HH, tmp, xpb, qkvb);
        k_attlog<<<(NN * HEADS) / 256, 256, 0, stream>>>(tmp, W + pattS + l * HEADS * DH,
                                                         W + pattD + l * HEADS * DH, als, ald,
                                                         gmax + l * 8);
        k_gat_node<<<NN, 128, 0, stream>>>(esrc, rowstart, cnt, als, ald, xpb, gatb, gmax + l * 8);
        // MHA branch
        k_mha_split<<<(NN / 64) * HEADS * KSPLIT, 256, 0, stream>>>(qkvb, pmb, plb, pob);
        k_mha_comb<<<(NN * HH) / 256, 256, 0, stream>>>(pmb, plb, pob, ahi, alo);
        // w_o projection + combine (residuals + BN0/BN1) fused
        k_gemm_wo<<<dim3(NN / 32, HH / 64), 128, 0, stream>>>(ahi, alo,
                                                              (u16*)(W + bw_o) + (size_t)l * HH * HH,
                                                              W + pb_o + l * HH, gatb, hbuf,
                                                              W + pb_gat + l * HH, W + pbn_g + l * 3 * HH,
                                                              W + pbn_b + l * 3 * HH, tmp, ohi, olo);
        // MLP
        k_mgemm<<<dim3(NN / 32, 256 / 64), 128, 0, stream>>>(ohi, olo,
                                                             (u16*)(W + bw1) + (size_t)l * 2 * HH * HH,
                                                             W + pb1 + l * 2 * HH, nullptr, nullptr,
                                                             mhi, mlo, HH, 2 * HH, 1);
        k_gemm_w2<<<dim3(NN / 32, HH / 64), 128, 0, stream>>>(mhi, mlo,
                                                              (u16*)(W + bw2) + (size_t)l * HH * 2 * HH,
                                                              W + pb2 + l * HH, tmp,
                                                              W + pbn_g + l * 3 * HH + 2 * HH,
                                                              W + pbn_b + l * 3 * HH + 2 * HH,
                                                              hbuf, hhi, hlo);
    }
    k_out<<<NN, 64, 0, stream>>>(hbuf, W + pw_out, W + pb_out, d_out, iflag);
}